// Round 4
// baseline (5310.661 us; speedup 1.0000x reference)
//
#include <hip/hip_runtime.h>

// ---------------- problem constants ----------------
#define B_ 32
#define S_ 64
#define C_ 512
#define E_ 256
#define H_ 512
#define V_ 32000
#define T_ 32
#define NBLK 256       // grid blocks (persistent kernel)
#define NTHR 512       // threads per block (8 waves)
#define ND 200         // scan blocks (200*160 = 32000)
#define VROWS 160      // vocab rows per scan block
#define START_TOK 1
#define DELTA 0.25f    // refine margin (fp8 logit err sigma ~0.01)
#define FSC 16.0f      // fp8 encode scale (w*16, h*16 -> product/256)
#define BH (B_ * H_)

// ---------------- workspace layout (float offsets) ----------------
#define OFF_BAR  0          // barrier: 8 group counters @k*32, g8 @256, gen @288
#define OFF_CS   512        // cscore[32][64]
#define OFF_LSEA 2560       // lse[32 t][32 b]
#define OFF_A2V  3584       // top2 cand value [32 b][512] (400 used)
#define OFF_A2I  19968      // top2 cand index [32 b][512]
#define OFF_LSM  36352      // lse partial max [32][256] (200 used)
#define OFF_LSS  44544      // lse partial sum [32][256]
#define OFF_INP  52736      // attn part of input [32 b][512]
#define OFF_H0   69120      // h0[2][32 b][512] ping-pong
#define OFF_H1   101888     // h1[2][32 b][512] ping-pong
#define OFF_H1F8 134656     // uchar[32 b][512] fp8 h1 (x16 scale)
#define OFF_H1BF 138752     // ushort[1024][512] bf16 h1 history
#define OFF_WOBF 400896     // ushort[32000][512] bf16 Wo
#define WS_FLOATS 8592896   // ~34.4 MB

typedef unsigned long long ull;
typedef __attribute__((ext_vector_type(8))) short bf16x8;
typedef __attribute__((ext_vector_type(4))) float f32x4;

struct Params {
  const float* ctx; const float* embed; const float* Wa;
  const float* Wih0; const float* Whh0; const float* bih0; const float* bhh0;
  const float* Wih1; const float* Whh1; const float* bih1; const float* bhh1;
  const float* Wo; const float* bo;
  float* ws; float* out;
};

__device__ __forceinline__ float sigf(float x) { return 1.0f / (1.0f + expf(-x)); }

__device__ __forceinline__ unsigned short f2bf(float f) {  // RNE f32->bf16
  unsigned u = __builtin_bit_cast(unsigned, f);
  unsigned r = (u + 0x7FFFu + ((u >> 16) & 1u)) >> 16;
  return (unsigned short)r;
}

// f32 -> OCP e4m3fn (RNE). Assumes |x| < 448, finite.
__device__ __forceinline__ unsigned char f2e4m3(float x) {
  unsigned u = __builtin_bit_cast(unsigned, x);
  unsigned s = (u >> 24) & 0x80u;
  float ax = fabsf(x);
  if (ax < 0.015625f) {                 // subnormal: quantum 2^-9
    int n = (int)rintf(ax * 512.f);     // 0..8 (8 -> smallest normal)
    return (unsigned char)(s | (unsigned)n);
  }
  int e = (int)((u >> 23) & 0xff);
  unsigned m = u & 0x7fffffu;
  unsigned r = m + 0x7ffffu + ((m >> 20) & 1u);  // RNE to 3 mantissa bits
  if (r >= 0x800000u) { r = 0; e += 1; }
  unsigned m3 = (r >> 20) & 7u;
  int et = e - 127 + 7;
  if (et > 15) return (unsigned char)(s | 0x7e);
  return (unsigned char)(s | ((unsigned)et << 3) | m3);
}

__device__ __forceinline__ void lse_merge(float& m, float& s, float m2, float s2) {
  float M = fmaxf(m, m2);
  s = s * expf(m - M) + s2 * expf(m2 - M);
  m = M;
}

// rotated byte address within a [rows][512B] LDS tile (conflict-free b64 frags)
__device__ __forceinline__ int rotA(int row, int kb) {
  return (row << 9) + ((kb + ((row & 15) << 5)) & 511);
}

// ---- coherent (L2-bypass) scalar access for mutable cross-block data ----
__device__ __forceinline__ float ld_cf(const float* p) {
  return __hip_atomic_load(p, __ATOMIC_RELAXED, __HIP_MEMORY_SCOPE_AGENT);
}
__device__ __forceinline__ void st_cf(float* p, float v) {
  __hip_atomic_store(p, v, __ATOMIC_RELAXED, __HIP_MEMORY_SCOPE_AGENT);
}
__device__ __forceinline__ void st_ci(int* p, int v) {
  __hip_atomic_store(p, v, __ATOMIC_RELAXED, __HIP_MEMORY_SCOPE_AGENT);
}

// -------- hierarchical grid barrier, no L2-invalidating fences --------
__device__ __forceinline__ void gbar(unsigned* ws) {
  __syncthreads();
  if (threadIdx.x == 0) {
    unsigned* cnt = ws + ((blockIdx.x & 7) << 5);  // 128B-spaced group counters
    unsigned* g8  = ws + 256;
    unsigned* gen = ws + 288;
    asm volatile("s_waitcnt vmcnt(0) lgkmcnt(0)" ::: "memory");
    unsigned g = __hip_atomic_load(gen, __ATOMIC_RELAXED, __HIP_MEMORY_SCOPE_AGENT);
    asm volatile("s_waitcnt vmcnt(0)" ::: "memory");
    unsigned a = __hip_atomic_fetch_add(cnt, 1u, __ATOMIC_RELAXED, __HIP_MEMORY_SCOPE_AGENT);
    if (a == 31u) {
      __hip_atomic_store(cnt, 0u, __ATOMIC_RELAXED, __HIP_MEMORY_SCOPE_AGENT);
      asm volatile("s_waitcnt vmcnt(0)" ::: "memory");
      unsigned a2 = __hip_atomic_fetch_add(g8, 1u, __ATOMIC_RELAXED, __HIP_MEMORY_SCOPE_AGENT);
      if (a2 == 7u) {
        __hip_atomic_store(g8, 0u, __ATOMIC_RELAXED, __HIP_MEMORY_SCOPE_AGENT);
        asm volatile("s_waitcnt vmcnt(0)" ::: "memory");
        __hip_atomic_store(gen, g + 1u, __ATOMIC_RELAXED, __HIP_MEMORY_SCOPE_AGENT);
      }
    }
    while (__hip_atomic_load(gen, __ATOMIC_RELAXED, __HIP_MEMORY_SCOPE_AGENT) == g)
      __builtin_amdgcn_s_sleep(2);
    asm volatile("" ::: "memory");
  }
  __syncthreads();
}

// ---------------- prologue kernels ----------------
__global__ void __launch_bounds__(256) zero_k(float* wsf) {
  const unsigned i = blockIdx.x * 256u + threadIdx.x;
  if (i < 512u) ((unsigned*)wsf)[i] = 0u;
  if (i < 65536u) wsf[OFF_H0 + i] = 0.0f;   // h0[2] + h1[2] contiguous
}

__global__ void __launch_bounds__(256) cscore_k(const float* __restrict__ ctx,
                                                const float* __restrict__ Wa,
                                                const float* __restrict__ ba,
                                                float* __restrict__ wsf) {
  const int b = blockIdx.x;
  const int s = threadIdx.x >> 2, q = threadIdx.x & 3;
  const float* cp = ctx + ((size_t)b * S_ + s) * C_ + q * 128;
  const float* wp = Wa + H_ + q * 128;     // context half of Wa
  float acc = 0.f;
#pragma unroll 8
  for (int k = 0; k < 128; ++k) acc = fmaf(cp[k], wp[k], acc);
  acc += __shfl_xor(acc, 1);
  acc += __shfl_xor(acc, 2);
  if (q == 0) wsf[OFF_CS + b * S_ + s] = acc + ba[0];
}

__global__ void __launch_bounds__(256) cvt_wobf(const float* __restrict__ wo,
                                                unsigned short* __restrict__ dst) {
  const size_t i = ((size_t)blockIdx.x * 256u + threadIdx.x) * 4;
  float4 v = *(const float4*)(wo + i);
  ushort4 o;
  o.x = f2bf(v.x); o.y = f2bf(v.y); o.z = f2bf(v.z); o.w = f2bf(v.w);
  *(ushort4*)(dst + i) = o;
}

// ---------------- main persistent kernel ----------------
__global__ void __launch_bounds__(NTHR) mtad_main(Params p) {
  float* wsf = p.ws;
  int* wsi = (int*)p.ws;
  unsigned* barp = (unsigned*)p.ws;
  unsigned char* h1f8 = (unsigned char*)(wsf + OFF_H1F8);
  unsigned short* h1bf = (unsigned short*)(wsf + OFF_H1BF);
  const int bk = blockIdx.x, tx = threadIdx.x;
  const int ug = bk & 31, bg = bk >> 5, b4 = bg * 4;

  __shared__ __align__(16) unsigned char woL[VROWS * 512];   // 80 KB persistent fp8 Wo
  __shared__ __align__(16) char SMEM[38912];                 // phase-dependent blob
  __shared__ float wlds[S_];
  __shared__ float hout[64];
  __shared__ float shsS;
  __shared__ int   stok[4];
  __shared__ float scrM[8], scrV[8], scrLm[8], scrLs[8];
  __shared__ int   scrI[8];

  // ---------- pre-loop: load Wo->LDS (scan blocks); attention for t=0 ----------
  if (bk < ND) {
    const int v0 = bk * VROWS;
#pragma unroll 2
    for (int i = 0; i < 40; ++i) {
      const int d = i * NTHR + tx;           // dword 0..20479
      const int row = d >> 7, kb = (d & 127) << 2;
      float4 w = *(const float4*)(p.Wo + (size_t)(v0 + row) * H_ + kb);
      unsigned q = (unsigned)f2e4m3(w.x * FSC) | ((unsigned)f2e4m3(w.y * FSC) << 8)
                 | ((unsigned)f2e4m3(w.z * FSC) << 16) | ((unsigned)f2e4m3(w.w * FSC) << 24);
      *(unsigned*)&woL[rotA(row, kb)] = q;
    }
  } else if (bk < ND + B_) {
    const int b = bk - ND;                    // attention for t=0, h1 = 0
    if (tx < S_) {
      float sc = tanhf(wsf[OFF_CS + b * S_ + tx]);
      float e = expf(sc); float sum = e;
#pragma unroll
      for (int d = 1; d < 64; d <<= 1) sum += __shfl_xor(sum, d);
      float w = e / sum; wlds[tx] = w;
      p.out[(size_t)B_ * T_ * V_ + ((size_t)b * T_ + 0) * S_ + tx] = w;
    }
    __syncthreads();
    float a0 = 0.f;
    const float* cb = p.ctx + (size_t)b * S_ * C_ + tx;
#pragma unroll 8
    for (int s = 0; s < S_; ++s) a0 = fmaf(wlds[s], cb[(size_t)s * C_], a0);
    st_cf(wsf + OFF_INP + (size_t)b * 512 + tx, a0);
  }
  gbar(barp);

  for (int t = 0; t < T_; ++t) {
    const int par = t & 1;
    // ======== Phase B: token resolve + embed + GRU layer 0 (all blocks) ========
    {
      float* sh1r  = (float*)SMEM;              // [4][512] h1_{t-1} for refine
      float* sacts = (float*)(SMEM + 8192);     // [4][768] (embed|attn)
      float* sh0   = sacts + 4 * 768;           // [4][512] h0_prev
      const int lb = tx >> 7, gtx = tx & 127, b = b4 + lb;
      const int gw = (tx >> 6) & 1, l64 = tx & 63;
      // stage attn, h0prev, h1prev
      {
        const ull* pInp = (const ull*)(wsf + OFF_INP);
        const ull* pH0  = (const ull*)(wsf + OFF_H0 + par * BH);
        const ull* pH1  = (const ull*)(wsf + OFF_H1 + par * BH);
        ull va[2], vh[2], vr[2];
#pragma unroll
        for (int k = 0; k < 2; ++k) {
          const int iu = k * NTHR + tx, bb = iu >> 8, cc = iu & 255;
          const ull* a1 = pInp + (size_t)(b4 + bb) * 256 + cc;
          const ull* a2 = pH0 + (size_t)(b4 + bb) * 256 + cc;
          const ull* a3 = pH1 + (size_t)(b4 + bb) * 256 + cc;
          asm volatile("global_load_dwordx2 %0, %1, off sc0 sc1" : "=v"(va[k]) : "v"(a1));
          asm volatile("global_load_dwordx2 %0, %1, off sc0 sc1" : "=v"(vh[k]) : "v"(a2));
          asm volatile("global_load_dwordx2 %0, %1, off sc0 sc1" : "=v"(vr[k]) : "v"(a3));
        }
        asm volatile("s_waitcnt vmcnt(0)" ::: "memory");
#pragma unroll
        for (int k = 0; k < 2; ++k) {
          const int iu = k * NTHR + tx, bb = iu >> 8, cc = iu & 255;
          *(ull*)&sacts[bb * 768 + 256 + cc * 2] = va[k];
          *(ull*)&sh0[bb * 512 + cc * 2] = vh[k];
          *(ull*)&sh1r[bb * 512 + cc * 2] = vr[k];
        }
      }
      if (t > 0) {
        // load candidates (400) + lse partials (200) for batch b
        float cv[4]; int ci[4];
        cv[3] = -3.0e38f; ci[3] = 0x7fffffff;
        float lm0, ls0, lm1 = -3.0e38f, ls1 = 0.f;
        const float* pv = wsf + OFF_A2V + (size_t)b * 512 + gtx;
        const int*   pi = wsi + OFF_A2I + (size_t)b * 512 + gtx;
        const float* pm = wsf + OFF_LSM + (size_t)b * 256 + gtx;
        const float* ps = wsf + OFF_LSS + (size_t)b * 256 + gtx;
        asm volatile("global_load_dword %0, %1, off sc0 sc1" : "=v"(cv[0]) : "v"(pv));
        asm volatile("global_load_dword %0, %1, off sc0 sc1" : "=v"(cv[1]) : "v"(pv + 128));
        asm volatile("global_load_dword %0, %1, off sc0 sc1" : "=v"(cv[2]) : "v"(pv + 256));
        asm volatile("global_load_dword %0, %1, off sc0 sc1" : "=v"(ci[0]) : "v"(pi));
        asm volatile("global_load_dword %0, %1, off sc0 sc1" : "=v"(ci[1]) : "v"(pi + 128));
        asm volatile("global_load_dword %0, %1, off sc0 sc1" : "=v"(ci[2]) : "v"(pi + 256));
        if (gtx < 16) {
          asm volatile("global_load_dword %0, %1, off sc0 sc1" : "=v"(cv[3]) : "v"(pv + 384));
          asm volatile("global_load_dword %0, %1, off sc0 sc1" : "=v"(ci[3]) : "v"(pi + 384));
        }
        asm volatile("global_load_dword %0, %1, off sc0 sc1" : "=v"(lm0) : "v"(pm));
        asm volatile("global_load_dword %0, %1, off sc0 sc1" : "=v"(ls0) : "v"(ps));
        if (gtx < 72) {
          asm volatile("global_load_dword %0, %1, off sc0 sc1" : "=v"(lm1) : "v"(pm + 128));
          asm volatile("global_load_dword %0, %1, off sc0 sc1" : "=v"(ls1) : "v"(ps + 128));
        }
        asm volatile("s_waitcnt vmcnt(0)"
                     : "+v"(cv[0]), "+v"(cv[1]), "+v"(cv[2]), "+v"(cv[3]),
                       "+v"(ci[0]), "+v"(ci[1]), "+v"(ci[2]), "+v"(ci[3]),
                       "+v"(lm0), "+v"(ls0), "+v"(lm1), "+v"(ls1) :: "memory");
        float M = fmaxf(fmaxf(cv[0], cv[1]), fmaxf(cv[2], cv[3]));
#pragma unroll
        for (int d = 1; d < 64; d <<= 1) M = fmaxf(M, __shfl_xor(M, d));
        if (l64 == 0) scrM[lb * 2 + gw] = M;
        __syncthreads();                       // publishes staging + scrM
        M = fmaxf(scrM[lb * 2], scrM[lb * 2 + 1]);
        // refine candidates near the fp8 max with exact fp32 dots
        float bv = -3.0e38f; int bi = 0x7fffffff;
#pragma unroll
        for (int k = 0; k < 4; ++k) {
          if (cv[k] >= M - DELTA && ci[k] < V_) {
            const float* wr = p.Wo + (size_t)ci[k] * H_;
            const float* hr = sh1r + lb * 512;
            float a0 = 0.f, a1 = 0.f, a2 = 0.f, a3 = 0.f;
            for (int kk = 0; kk < H_; kk += 4) {
              float4 w = *(const float4*)(wr + kk);
              a0 = fmaf(hr[kk], w.x, a0); a1 = fmaf(hr[kk + 1], w.y, a1);
              a2 = fmaf(hr[kk + 2], w.z, a2); a3 = fmaf(hr[kk + 3], w.w, a3);
            }
            float ex = ((a0 + a1) + (a2 + a3)) + p.bo[ci[k]];
            if (ex > bv || (ex == bv && ci[k] < bi)) { bv = ex; bi = ci[k]; }
          }
        }
#pragma unroll
        for (int d = 1; d < 64; d <<= 1) {
          float v2 = __shfl_xor(bv, d); int i2 = __shfl_xor(bi, d);
          if (v2 > bv || (v2 == bv && i2 < bi)) { bv = v2; bi = i2; }
        }
        float m = lm0, s = ls0;
        lse_merge(m, s, lm1, ls1);
#pragma unroll
        for (int d = 1; d < 64; d <<= 1) {
          float m2 = __shfl_xor(m, d), s2 = __shfl_xor(s, d);
          lse_merge(m, s, m2, s2);
        }
        if (l64 == 0) {
          scrV[lb * 2 + gw] = bv; scrI[lb * 2 + gw] = bi;
          scrLm[lb * 2 + gw] = m; scrLs[lb * 2 + gw] = s;
        }
        __syncthreads();
        if (gtx == 0) {
          float v0v = scrV[lb * 2], v1v = scrV[lb * 2 + 1];
          int i0v = scrI[lb * 2], i1v = scrI[lb * 2 + 1];
          stok[lb] = (v1v > v0v || (v1v == v0v && i1v < i0v)) ? i1v : i0v;
          if (ug == 0) {
            float mm = scrLm[lb * 2], ss = scrLs[lb * 2];
            lse_merge(mm, ss, scrLm[lb * 2 + 1], scrLs[lb * 2 + 1]);
            st_cf(wsf + OFF_LSEA + (t - 1) * B_ + b, mm + logf(ss));
          }
        }
      } else {
        if (tx < 4) stok[tx] = START_TOK;
      }
      __syncthreads();                          // stok (+ staging at t==0)
      // embed stage
#pragma unroll
      for (int k = 0; k < 2; ++k) {
        const int idx = k * NTHR + tx;          // 0..1023
        const int bb = idx >> 8, e = idx & 255;
        sacts[bb * 768 + e] = p.embed[(size_t)stok[bb] * E_ + e];
      }
      __syncthreads();
      // GRU0 compute: unit j = ug*16+u, 4 batches, K split over 32 lanes
      const int u = tx >> 5, l = tx & 31;
      const int j = ug * 16 + u;
      float red[16];
#pragma unroll
      for (int q = 0; q < 16; ++q) red[q] = 0.f;
#pragma unroll
      for (int g = 0; g < 3; ++g) {
        const float* wx = p.Wih0 + (size_t)(g * H_ + j) * 768 + l * 24;
        float* dx = (g < 2) ? &red[g * 4] : &red[8];
#pragma unroll
        for (int c = 0; c < 6; ++c) {
          const float4 w = *(const float4*)(wx + c * 4);
#pragma unroll
          for (int b2 = 0; b2 < 4; ++b2) {
            const float* a = &sacts[b2 * 768 + l * 24 + c * 4];
            dx[b2] = fmaf(w.x, a[0], dx[b2]); dx[b2] = fmaf(w.y, a[1], dx[b2]);
            dx[b2] = fmaf(w.z, a[2], dx[b2]); dx[b2] = fmaf(w.w, a[3], dx[b2]);
          }
        }
        const float* wh = p.Whh0 + (size_t)(g * H_ + j) * H_ + l * 16;
        float* dh = (g < 2) ? &red[g * 4] : &red[12];
#pragma unroll
        for (int c = 0; c < 4; ++c) {
          const float4 w = *(const float4*)(wh + c * 4);
#pragma unroll
          for (int b2 = 0; b2 < 4; ++b2) {
            const float* a = &sh0[b2 * 512 + l * 16 + c * 4];
            dh[b2] = fmaf(w.x, a[0], dh[b2]); dh[b2] = fmaf(w.y, a[1], dh[b2]);
            dh[b2] = fmaf(w.z, a[2], dh[b2]); dh[b2] = fmaf(w.w, a[3], dh[b2]);
          }
        }
      }
#pragma unroll
      for (int d = 1; d < 32; d <<= 1)
#pragma unroll
        for (int q = 0; q < 16; ++q) red[q] += __shfl_xor(red[q], d);
      if (l < 4) {
        const float rr = sigf(red[l] + p.bih0[j] + p.bhh0[j]);
        const float zz = sigf(red[4 + l] + p.bih0[H_ + j] + p.bhh0[H_ + j]);
        const float nn = tanhf(red[8 + l] + p.bih0[2 * H_ + j] +
                               rr * (red[12 + l] + p.bhh0[2 * H_ + j]));
        const float hp = sh0[l * 512 + j];
        st_cf(wsf + OFF_H0 + (1 - par) * BH + (size_t)(b4 + l) * H_ + j,
              (1.f - zz) * nn + zz * hp);
      }
    }
    gbar(barp);
    // ================= Phase C: GRU layer 1 + h1 stores =================
    {
      float* sx = (float*)SMEM;                 // [4][512] h0_new
      float* sh = sx + 2048;                    // [4][512] h1_prev
      {
        const ull* pX = (const ull*)(wsf + OFF_H0 + (1 - par) * BH);
        const ull* pH = (const ull*)(wsf + OFF_H1 + par * BH);
        ull vx[2], vh2[2];
#pragma unroll
        for (int k = 0; k < 2; ++k) {
          const int iu = k * NTHR + tx, bb = iu >> 8, cc = iu & 255;
          const ull* a1 = pX + (size_t)(b4 + bb) * 256 + cc;
          const ull* a2 = pH + (size_t)(b4 + bb) * 256 + cc;
          asm volatile("global_load_dwordx2 %0, %1, off sc0 sc1" : "=v"(vx[k]) : "v"(a1));
          asm volatile("global_load_dwordx2 %0, %1, off sc0 sc1" : "=v"(vh2[k]) : "v"(a2));
        }
        asm volatile("s_waitcnt vmcnt(0)" ::: "memory");
#pragma unroll
        for (int k = 0; k < 2; ++k) {
          const int iu = k * NTHR + tx, bb = iu >> 8, cc = iu & 255;
          *(ull*)&sx[bb * 512 + cc * 2] = vx[k];
          *(ull*)&sh[bb * 512 + cc * 2] = vh2[k];
        }
      }
      __syncthreads();
      const int u = tx >> 5, l = tx & 31;
      const int j = ug * 16 + u;
      float red[16];
#pragma unroll
      for (int q = 0; q < 16; ++q) red[q] = 0.f;
#pragma unroll
      for (int g = 0; g < 3; ++g) {
        const float* wx = p.Wih1 + (size_t)(g * H_ + j) * H_ + l * 16;
        float* dx = (g < 2) ? &red[g * 4] : &red[8];
#pragma unroll
        for (int c = 0; c < 4; ++c) {
          const float4 w = *(const float4*)(wx + c * 4);
#pragma unroll
          for (int b2 = 0; b2 < 4; ++b2) {
            const float* a = &sx[b2 * 512 + l * 16 + c * 4];
            dx[b2] = fmaf(w.x, a[0], dx[b2]); dx[b2] = fmaf(w.y, a[1], dx[b2]);
            dx[b2] = fmaf(w.z, a[2], dx[b2]); dx[b2] = fmaf(w.w, a[3], dx[b2]);
          }
        }
        const float* wh = p.Whh1 + (size_t)(g * H_ + j) * H_ + l * 16;
        float* dh = (g < 2) ? &red[g * 4] : &red[12];
#pragma unroll
        for (int c = 0; c < 4; ++c) {
          const float4 w = *(const float4*)(wh + c * 4);
#pragma unroll
          for (int b2 = 0; b2 < 4; ++b2) {
            const float* a = &sh[b2 * 512 + l * 16 + c * 4];
            dh[b2] = fmaf(w.x, a[0], dh[b2]); dh[b2] = fmaf(w.y, a[1], dh[b2]);
            dh[b2] = fmaf(w.z, a[2], dh[b2]); dh[b2] = fmaf(w.w, a[3], dh[b2]);
          }
        }
      }
#pragma unroll
      for (int d = 1; d < 32; d <<= 1)
#pragma unroll
        for (int q = 0; q < 16; ++q) red[q] += __shfl_xor(red[q], d);
      if (l < 4) {
        const float rr = sigf(red[l] + p.bih1[j] + p.bhh1[j]);
        const float zz = sigf(red[4 + l] + p.bih1[H_ + j] + p.bhh1[H_ + j]);
        const float nn = tanhf(red[8 + l] + p.bih1[2 * H_ + j] +
                               rr * (red[12 + l] + p.bhh1[2 * H_ + j]));
        const float hp = sh[l * 512 + j];
        const float hnew = (1.f - zz) * nn + zz * hp;
        st_cf(wsf + OFF_H1 + (1 - par) * BH + (size_t)(b4 + l) * H_ + j, hnew);
        hout[u * 4 + l] = hnew;
      }
      __syncthreads();
      if (tx < 32) {   // bf16 pack (2 units / dword) for final GEMM
        const int b2 = tx & 3, pp = tx >> 2;
        const float h0v = hout[(pp * 2) * 4 + b2];
        const float h1v = hout[(pp * 2 + 1) * 4 + b2];
        const unsigned pk = (unsigned)f2bf(h0v) | ((unsigned)f2bf(h1v) << 16);
        st_ci((int*)(h1bf + ((size_t)t * B_ + b4 + b2) * H_ + ug * 16 + pp * 2), (int)pk);
      }
      if (tx >= 64 && tx < 80) {  // fp8 pack (4 units / dword) for scan
        const int tt2 = tx - 64;
        const int b2 = tt2 & 3, q = tt2 >> 2;
        unsigned pk = 0;
#pragma unroll
        for (int e = 0; e < 4; ++e)
          pk |= (unsigned)f2e4m3(hout[(q * 4 + e) * 4 + b2] * FSC) << (8 * e);
        st_ci((int*)(h1f8 + ((size_t)(b4 + b2) * H_) + ug * 16 + q * 4), (int)pk);
      }
    }
    gbar(barp);
    // ===== Phase D/A: fp8 MFMA vocab scan (200 blocks) || attention t+1 (32) =====
    {
      if (bk < ND) {
        const int v0 = bk * VROWS;
        unsigned char* a8L = (unsigned char*)SMEM;     // [32][512B] fp8 h1, rotated
        float* slog = (float*)(SMEM + 16384);          // [32][168]
        {
          const ull* pH8 = (const ull*)h1f8;
          ull v[4];
#pragma unroll
          for (int m2 = 0; m2 < 4; ++m2)
            asm volatile("global_load_dwordx2 %0, %1, off sc0 sc1"
                         : "=v"(v[m2]) : "v"(pH8 + tx * 4 + m2));
          asm volatile("s_waitcnt vmcnt(0)" ::: "memory");
#pragma unroll
          for (int m2 = 0; m2 < 4; ++m2) {
            const int i2 = tx * 4 + m2;
            const int bb = i2 >> 6, kb = (i2 & 63) << 3;
            *(ull*)&a8L[rotA(bb, kb)] = v[m2];
          }
        }
        __syncthreads();
        const int w = tx >> 6, l = tx & 63, lr = l & 15, lk = l >> 4;
        for (int tid = w; tid < 20; tid += 8) {        // 10 vtiles x 2 btiles
          const int vt = tid >> 1, bt = tid & 1;
          f32x4 acc = {0.f, 0.f, 0.f, 0.f};
          const int ar = bt * 16 + lr, br = vt * 16 + lr;
#pragma unroll
          for (int kc = 0; kc < 16; ++kc) {
            const int kb = kc * 32 + lk * 8;
            long av = *(const long*)&a8L[rotA(ar, kb)];
            long bv2 = *(const long*)&woL[rotA(br, kb)];
            acc = __builtin_amdgcn_mfma_f32_16x16x32_fp8_fp8(av, bv2, acc, 0, 0, 0);
          }
#pragma unroll
          for (int r = 0; r < 4; ++r)
            slog[(bt * 16 + lk * 4 + r) * 168 + vt * 16 + lr] = acc[r] * (1.f / 256.f);
        }
        __syncthreads();
        {
          const int bb = tx >> 4, g = tx & 15;
          float v1 = -3.0e38f, v2 = -3.0e38f; int i1 = 0x7fffffff, i2 = 0x7fffffff;
          float m = -3.0e38f, s = 0.f;
#pragma unroll
          for (int jj = 0; jj < 10; ++jj) {
            const int vl = g * 10 + jj;
            const float val = slog[bb * 168 + vl] + p.bo[v0 + vl];
            const int idx = v0 + vl;
            if (val > v1 || (val == v1 && idx < i1)) { v2 = v1; i2 = i1; v1 = val; i1 = idx; }
            else if (val > v2 || (val == v2 && idx < i2)) { v2 = val; i2 = idx; }
            if (val > m) { s = s * expf(m - val) + 1.f; m = val; } else s += expf(val - m);
          }
#pragma unroll
          for (int d = 1; d < 16; d <<= 1) {
            float w1 = __shfl_xor(v1, d); int j1 = __shfl_xor(i1, d);
            float w2 = __shfl_xor(v2, d); int j2 = __shfl_xor(i2, d);
            float m2 = __shfl_xor(m, d);  float s2 = __shfl_xor(s, d);
            if (w1 > v1 || (w1 == v1 && j1 < i1)) { v2 = v1; i2 = i1; v1 = w1; i1 = j1; }
            else if (w1 > v2 || (w1 == v2 && j1 < i2)) { v2 = w1; i2 = j1; }
            if (w2 > v2 || (w2 == v2 && j2 < i2)) {
              if (w2 > v1 || (w2 == v1 && j2 < i1)) { v2 = v1; i2 = i1; v1 = w2; i1 = j2; }
              else { v2 = w2; i2 = j2; }
            }
            lse_merge(m, s, m2, s2);
          }
          if (g == 0) {
            st_cf(wsf + OFF_A2V + (size_t)bb * 512 + bk * 2, v1);
            st_cf(wsf + OFF_A2V + (size_t)bb * 512 + bk * 2 + 1, v2);
            st_ci(wsi + OFF_A2I + (size_t)bb * 512 + bk * 2, i1);
            st_ci(wsi + OFF_A2I + (size_t)bb * 512 + bk * 2 + 1, i2);
            st_cf(wsf + OFF_LSM + (size_t)bb * 256 + bk, m);
            st_cf(wsf + OFF_LSS + (size_t)bb * 256 + bk, s);
          }
        }
      } else if (bk < ND + B_ && t < T_ - 1) {
        // attention for step t+1 using h1_t
        const int b = bk - ND;
        float* rv = (float*)SMEM;                 // [512]
        float* sh1a = (float*)(SMEM + 2048);      // [512]
        sh1a[tx] = ld_cf(wsf + OFF_H1 + (1 - par) * BH + (size_t)b * H_ + tx);
        __syncthreads();
        rv[tx] = sh1a[tx] * p.Wa[tx];
        __syncthreads();
        if (tx < 64) {
          float v = 0.f;
#pragma unroll
          for (int o = 0; o < 8; ++o) v += rv[tx + o * 64];
#pragma unroll
          for (int d = 1; d < 64; d <<= 1) v += __shfl_xor(v, d);
          if (tx == 0) shsS = v;
        }
        __syncthreads();
        if (tx < S_) {
          float sc = tanhf(shsS + wsf[OFF_CS + b * S_ + tx]);
          float e = expf(sc); float sum = e;
#pragma unroll
          for (int d = 1; d < 64; d <<= 1) sum += __shfl_xor(sum, d);
          float w2 = e / sum; wlds[tx] = w2;
          p.out[(size_t)B_ * T_ * V_ + ((size_t)b * T_ + (t + 1)) * S_ + tx] = w2;
        }
        __syncthreads();
        float a0 = 0.f;
        const float* cb = p.ctx + (size_t)b * S_ * C_ + tx;
#pragma unroll 8
        for (int s2 = 0; s2 < S_; ++s2) a0 = fmaf(wlds[s2], cb[(size_t)s2 * C_], a0);
        st_cf(wsf + OFF_INP + (size_t)b * 512 + tx, a0);
      }
    }
    if (t < T_ - 1) gbar(barp);
  }
}

// ---------------- epilogue: lse for last step ----------------
__global__ void __launch_bounds__(256) epi_lse(float* __restrict__ wsf) {
  const int b = blockIdx.x, tx = threadIdx.x;
  __shared__ float rm[256], rs[256];
  rm[tx] = (tx < ND) ? wsf[OFF_LSM + b * 256 + tx] : -3.0e38f;
  rs[tx] = (tx < ND) ? wsf[OFF_LSS + b * 256 + tx] : 0.f;
  __syncthreads();
  if (tx < 64) {
    float m = rm[tx], s = rs[tx];
#pragma unroll
    for (int o = 64; o < 256; o += 64) lse_merge(m, s, rm[tx + o], rs[tx + o]);
#pragma unroll
    for (int d = 1; d < 64; d <<= 1) {
      float m2 = __shfl_xor(m, d), s2 = __shfl_xor(s, d);
      lse_merge(m, s, m2, s2);
    }
    if (tx == 0) wsf[OFF_LSEA + 31 * B_ + b] = m + logf(s);
  }
}

// ---------------- final batched logp GEMM (bf16 MFMA) ----------------
__global__ void __launch_bounds__(256) gemm_logp(const unsigned short* __restrict__ h1bf,
                                                 const unsigned short* __restrict__ wobf,
                                                 const float* __restrict__ bo,
                                                 const float* __restrict__ lsea,
                                                 float* __restrict__ out) {
  __shared__ __align__(16) unsigned short As[2][128 * 40];  // rows padded to 80B
  __shared__ __align__(16) unsigned short Bs[2][128 * 40];
  const int tx = threadIdx.x;
  const int v0 = blockIdx.x * 128, m0 = blockIdx.y * 128;
  const int w = tx >> 6, l = tx & 63;
  const int wm = w >> 1, wn = w & 1;
  f32x4 acc[4][4];
#pragma unroll
  for (int i = 0; i < 4; ++i)
#pragma unroll
    for (int j = 0; j < 4; ++j) acc[i][j] = (f32x4){0.f, 0.f, 0.f, 0.f};

#define GSTAGE(ci, kc) {                                                        \
    _Pragma("unroll")                                                           \
    for (int e = 0; e < 2; ++e) {                                               \
      const int seg = tx * 2 + e, row = seg >> 2, s = seg & 3;                  \
      *(uint4*)&As[ci][row * 40 + s * 8] =                                      \
          *(const uint4*)(h1bf + (size_t)(m0 + row) * H_ + (kc) * 32 + s * 8);  \
      *(uint4*)&Bs[ci][row * 40 + s * 8] =                                      \
          *(const uint4*)(wobf + (size_t)(v0 + row) * H_ + (kc) * 32 + s * 8);  \
    } }

  GSTAGE(0, 0);
  __syncthreads();
  for (int kc = 0; kc < 16; ++kc) {
    const int cur = kc & 1;
    if (kc < 15) GSTAGE(cur ^ 1, kc + 1);
    const int lk = (l >> 4) * 8, lr = l & 15;
    bf16x8 af[4], bf[4];
#pragma unroll
    for (int f = 0; f < 4; ++f) {
      af[f] = *(const bf16x8*)&As[cur][(wm * 64 + f * 16 + lr) * 40 + lk];
      bf[f] = *(const bf16x8*)&Bs[cur][(wn * 64 + f * 16 + lr) * 40 + lk];
    }
#pragma unroll
    for (int fm = 0; fm < 4; ++fm)
#pragma unroll
      for (int fn = 0; fn < 4; ++fn)
        acc[fm][fn] = __builtin_amdgcn_mfma_f32_16x16x32_bf16(af[fm], bf[fn], acc[fm][fn], 0, 0, 0);
    __syncthreads();
  }
#undef GSTAGE
  const int lr = l & 15, lq = l >> 4;
#pragma unroll
  for (int fm = 0; fm < 4; ++fm) {
#pragma unroll
    for (int fn = 0; fn < 4; ++fn) {
      const int v = v0 + wn * 64 + fn * 16 + lr;
      const float bov = bo[v];
#pragma unroll
      for (int r = 0; r < 4; ++r) {
        const int M = m0 + wm * 64 + fm * 16 + lq * 4 + r;
        const int tt = M >> 5, b = M & 31;
        out[((size_t)b * T_ + tt) * (size_t)V_ + v] = acc[fm][fn][r] + bov - lsea[tt * B_ + b];
      }
    }
  }
}

// ---------------- host launch ----------------
extern "C" void kernel_launch(void* const* d_in, const int* in_sizes, int n_in,
                              void* d_out, int out_size, void* d_ws, size_t ws_size,
                              hipStream_t stream) {
  (void)in_sizes; (void)n_in; (void)out_size;
  if (ws_size < (size_t)WS_FLOATS * sizeof(float)) return;  // workspace too small

  const float* ctx   = (const float*)d_in[0];
  // d_in[1] = max_len (scalar, == 32, hardcoded)
  const float* embed = (const float*)d_in[2];
  const float* Wa    = (const float*)d_in[3];
  const float* ba    = (const float*)d_in[4];
  const float* Wih0  = (const float*)d_in[5];
  const float* Whh0  = (const float*)d_in[6];
  const float* bih0  = (const float*)d_in[7];
  const float* bhh0  = (const float*)d_in[8];
  const float* Wih1  = (const float*)d_in[9];
  const float* Whh1  = (const float*)d_in[10];
  const float* bih1  = (const float*)d_in[11];
  const float* bhh1  = (const float*)d_in[12];
  const float* Wo    = (const float*)d_in[13];
  const float* bo    = (const float*)d_in[14];
  float* ws  = (float*)d_ws;
  float* out = (float*)d_out;

  zero_k<<<dim3(256), dim3(256), 0, stream>>>(ws);
  cscore_k<<<dim3(32), dim3(256), 0, stream>>>(ctx, Wa, ba, ws);
  cvt_wobf<<<dim3(16000), dim3(256), 0, stream>>>(Wo, (unsigned short*)(ws + OFF_WOBF));

  Params p;
  p.ctx = ctx; p.embed = embed; p.Wa = Wa;
  p.Wih0 = Wih0; p.Whh0 = Whh0; p.bih0 = bih0; p.bhh0 = bhh0;
  p.Wih1 = Wih1; p.Whh1 = Whh1; p.bih1 = bih1; p.bhh1 = bhh1;
  p.Wo = Wo; p.bo = bo; p.ws = ws; p.out = out;
  mtad_main<<<dim3(NBLK), dim3(NTHR), 0, stream>>>(p);

  epi_lse<<<dim3(32), dim3(256), 0, stream>>>(ws);
  gemm_logp<<<dim3(250, 8), dim3(256), 0, stream>>>(
      (const unsigned short*)(ws + OFF_H1BF), (const unsigned short*)(ws + OFF_WOBF),
      bo, ws + OFF_LSEA, out);
}

// Round 5
// 3770.802 us; speedup vs baseline: 1.4084x; 1.4084x over previous
//
#include <hip/hip_runtime.h>

// ---------------- problem constants ----------------
#define B_ 32
#define S_ 64
#define C_ 512
#define E_ 256
#define H_ 512
#define V_ 32000
#define T_ 32
#define NBLK 256       // grid blocks (persistent kernel)
#define NTHR 512       // threads per block (8 waves)
#define ND 250         // scan blocks (250*128 = 32000)
#define START_TOK 1
#define DELTA 0.05f    // refine margin (bf16 logit err sigma ~6e-4)
#define BH (B_ * H_)

// ---------------- workspace layout (float offsets) ----------------
#define OFF_BAR  0          // barrier: 8 group counters @k*32, g8 @256, gen @288
#define OFF_CS   512        // cscore[32][64]
#define OFF_LSEA 2560       // lse[32 t][32 b]
#define OFF_TOK  3584       // token[32] (int)
#define OFF_A2V  3648       // top2 cand value [32 b][512] (500 used)
#define OFF_A2I  20032      // top2 cand index [32 b][512] (int)
#define OFF_LSM  36416      // lse partial max [32][256] (250 used)
#define OFF_LSS  44608      // lse partial sum [32][256]
#define OFF_INP  52800      // attend [32 b][512]
#define OFF_H0   69184      // h0[2][32 b][512] ping-pong
#define OFF_H1   101952     // h1[2][32 b][512] ping-pong
#define OFF_H1BF 134720     // ushort[32 t * 32 b][512] bf16 h1 history
#define OFF_WOBF 396864     // ushort[32000][512] bf16 Wo
#define WS_FLOATS 8588864   // ~34.4 MB

typedef unsigned long long ull;
typedef __attribute__((ext_vector_type(8))) short bf16x8;
typedef __attribute__((ext_vector_type(4))) float f32x4;

struct Params {
  const float* ctx; const float* embed; const float* Wa;
  const float* Wih0; const float* Whh0; const float* bih0; const float* bhh0;
  const float* Wih1; const float* Whh1; const float* bih1; const float* bhh1;
  const float* Wo; const float* bo;
  float* ws; float* out;
};

__device__ __forceinline__ float sigf(float x) { return 1.0f / (1.0f + expf(-x)); }

__device__ __forceinline__ unsigned short f2bf(float f) {  // RNE f32->bf16
  unsigned u = __builtin_bit_cast(unsigned, f);
  unsigned r = (u + 0x7FFFu + ((u >> 16) & 1u)) >> 16;
  return (unsigned short)r;
}

__device__ __forceinline__ void lse_merge(float& m, float& s, float m2, float s2) {
  float M = fmaxf(m, m2);
  s = s * expf(m - M) + s2 * expf(m2 - M);
  m = M;
}

// ---- coherent (L2-bypass) access for mutable cross-block data ----
__device__ __forceinline__ float ld_cf(const float* p) {
  return __hip_atomic_load(p, __ATOMIC_RELAXED, __HIP_MEMORY_SCOPE_AGENT);
}
__device__ __forceinline__ void st_cf(float* p, float v) {
  __hip_atomic_store(p, v, __ATOMIC_RELAXED, __HIP_MEMORY_SCOPE_AGENT);
}
__device__ __forceinline__ int ld_ci(const int* p) {
  return __hip_atomic_load(p, __ATOMIC_RELAXED, __HIP_MEMORY_SCOPE_AGENT);
}
__device__ __forceinline__ void st_ci(int* p, int v) {
  __hip_atomic_store(p, v, __ATOMIC_RELAXED, __HIP_MEMORY_SCOPE_AGENT);
}

// -------- hierarchical grid barrier, no L2-invalidating fences --------
__device__ __forceinline__ void gbar(unsigned* ws) {
  __syncthreads();
  if (threadIdx.x == 0) {
    unsigned* cnt = ws + ((blockIdx.x & 7) << 5);
    unsigned* g8  = ws + 256;
    unsigned* gen = ws + 288;
    asm volatile("s_waitcnt vmcnt(0) lgkmcnt(0)" ::: "memory");
    unsigned g = __hip_atomic_load(gen, __ATOMIC_RELAXED, __HIP_MEMORY_SCOPE_AGENT);
    asm volatile("s_waitcnt vmcnt(0)" ::: "memory");
    unsigned a = __hip_atomic_fetch_add(cnt, 1u, __ATOMIC_RELAXED, __HIP_MEMORY_SCOPE_AGENT);
    if (a == 31u) {
      __hip_atomic_store(cnt, 0u, __ATOMIC_RELAXED, __HIP_MEMORY_SCOPE_AGENT);
      asm volatile("s_waitcnt vmcnt(0)" ::: "memory");
      unsigned a2 = __hip_atomic_fetch_add(g8, 1u, __ATOMIC_RELAXED, __HIP_MEMORY_SCOPE_AGENT);
      if (a2 == 7u) {
        __hip_atomic_store(g8, 0u, __ATOMIC_RELAXED, __HIP_MEMORY_SCOPE_AGENT);
        asm volatile("s_waitcnt vmcnt(0)" ::: "memory");
        __hip_atomic_store(gen, g + 1u, __ATOMIC_RELAXED, __HIP_MEMORY_SCOPE_AGENT);
      }
    }
    while (__hip_atomic_load(gen, __ATOMIC_RELAXED, __HIP_MEMORY_SCOPE_AGENT) == g)
      __builtin_amdgcn_s_sleep(2);
    asm volatile("" ::: "memory");
  }
  __syncthreads();
}

// ---------------- prologue kernels ----------------
__global__ void __launch_bounds__(256) zero_k(float* wsf) {
  const unsigned i = blockIdx.x * 256u + threadIdx.x;
  if (i < 512u) ((unsigned*)wsf)[i] = 0u;
  if (i < 65536u) wsf[OFF_H0 + i] = 0.0f;   // h0[2] + h1[2] contiguous
}

__global__ void __launch_bounds__(256) cscore_k(const float* __restrict__ ctx,
                                                const float* __restrict__ Wa,
                                                const float* __restrict__ ba,
                                                float* __restrict__ wsf) {
  const int b = blockIdx.x;
  const int s = threadIdx.x >> 2, q = threadIdx.x & 3;
  const float* cp = ctx + ((size_t)b * S_ + s) * C_ + q * 128;
  const float* wp = Wa + H_ + q * 128;     // context half of Wa
  float acc = 0.f;
#pragma unroll 8
  for (int k = 0; k < 128; ++k) acc = fmaf(cp[k], wp[k], acc);
  acc += __shfl_xor(acc, 1);
  acc += __shfl_xor(acc, 2);
  if (q == 0) wsf[OFF_CS + b * S_ + s] = acc + ba[0];
}

__global__ void __launch_bounds__(256) cvt_wobf(const float* __restrict__ wo,
                                                unsigned short* __restrict__ dst) {
  const size_t i = ((size_t)blockIdx.x * 256u + threadIdx.x) * 4;
  float4 v = *(const float4*)(wo + i);
  ushort4 o;
  o.x = f2bf(v.x); o.y = f2bf(v.y); o.z = f2bf(v.z); o.w = f2bf(v.w);
  *(ushort4*)(dst + i) = o;
}

// ---------------- main persistent kernel ----------------
__global__ void __launch_bounds__(NTHR) mtad_main(Params p) {
  float* wsf = p.ws;
  int* wsi = (int*)p.ws;
  unsigned* barp = (unsigned*)p.ws;
  unsigned short* h1bf = (unsigned short*)(wsf + OFF_H1BF);
  const unsigned short* wobf = (const unsigned short*)(wsf + OFF_WOBF);
  const int bk = blockIdx.x, tx = threadIdx.x;
  const int ug = bk & 31, bg = bk >> 5, b4 = bg * 4;

  __shared__ __align__(16) unsigned char woL[131072];  // 128 KB: this block's 128 bf16 Wo rows
  __shared__ __align__(16) char SMEM[20480];           // phase-dependent blob
  __shared__ float wlds[64];
  __shared__ float hout[64];
  __shared__ int   stok4[4];
  __shared__ float shsS, sMax;
  __shared__ int   slist[64];
  __shared__ int   scnt;

  // ---------- prologue: fill woL (swizzled) from WOBF ----------
  if (bk < ND) {
    const unsigned short* src = wobf + (size_t)bk * 128 * H_;
    for (int c = tx; c < 8192; c += NTHR) {
      const int row = c >> 6, cc = c & 63;
      uint4 v = *(const uint4*)(src + (size_t)row * H_ + cc * 8);
      *(uint4*)&woL[row * 1024 + ((cc * 16) ^ ((row & 7) << 4))] = v;
    }
  }
  gbar(barp);

  for (int t = 0; t < T_; ++t) {
    const int par = t & 1;
    // ========== Phase A: attention (blocks 0..31) || resolve (32..63) ==========
    if (bk < B_) {
      const int b = bk;
      float* rv   = (float*)SMEM;            // [512]
      float* sh1a = (float*)(SMEM + 2048);   // [512]
      sh1a[tx] = ld_cf(wsf + OFF_H1 + par * BH + (size_t)b * H_ + tx);
      __syncthreads();
      rv[tx] = sh1a[tx] * p.Wa[tx];
      __syncthreads();
      if (tx < 64) {
        float v = 0.f;
#pragma unroll
        for (int o = 0; o < NTHR; o += 64) v += rv[tx + o];
#pragma unroll
        for (int d = 1; d < 64; d <<= 1) v += __shfl_xor(v, d);
        if (tx == 0) shsS = v;
      }
      __syncthreads();
      if (tx < S_) {
        float sc = tanhf(shsS + wsf[OFF_CS + b * S_ + tx]);
        float e = expf(sc); float sum = e;
#pragma unroll
        for (int d = 1; d < 64; d <<= 1) sum += __shfl_xor(sum, d);
        float w = e / sum; wlds[tx] = w;
        p.out[(size_t)B_ * T_ * V_ + ((size_t)b * T_ + t) * S_ + tx] = w;
      }
      __syncthreads();
      {
        float a0 = 0.f;
        const float* cb = p.ctx + (size_t)b * S_ * C_ + tx;
#pragma unroll 8
        for (int s2 = 0; s2 < S_; ++s2) a0 = fmaf(wlds[s2], cb[(size_t)s2 * C_], a0);
        st_cf(wsf + OFF_INP + (size_t)b * H_ + tx, a0);
      }
    } else if (bk < 2 * B_ && t > 0) {
      const int b = bk - B_;
      float* rm   = (float*)(SMEM + 4096);   // [256]
      float* rs   = (float*)(SMEM + 5120);   // [256]
      float* sh1a = (float*)(SMEM + 6144);   // [512]
      float* rtmp = (float*)(SMEM + 8192);   // [512]
      sh1a[tx] = ld_cf(wsf + OFF_H1 + par * BH + (size_t)b * H_ + tx);
      float cv = -3.0e38f; int ci = 0x7fffffff;
      if (tx < 2 * ND) {
        cv = ld_cf(wsf + OFF_A2V + (size_t)b * 512 + tx);
        ci = ld_ci(wsi + OFF_A2I + (size_t)b * 512 + tx);
      }
      if (tx < 256) {
        rm[tx] = (tx < ND) ? ld_cf(wsf + OFF_LSM + (size_t)b * 256 + tx) : -3.0e38f;
        rs[tx] = (tx < ND) ? ld_cf(wsf + OFF_LSS + (size_t)b * 256 + tx) : 0.f;
      }
      rtmp[tx] = cv;
      __syncthreads();
      if (tx < 256) rtmp[tx] = fmaxf(rtmp[tx], rtmp[tx + 256]);
      if (tx < 128) lse_merge(rm[tx], rs[tx], rm[tx + 128], rs[tx + 128]);
      __syncthreads();
      if (tx < 64) {
        float M = fmaxf(fmaxf(rtmp[tx], rtmp[tx + 64]),
                        fmaxf(rtmp[tx + 128], rtmp[tx + 192]));
        float m = rm[tx], s = rs[tx];
        lse_merge(m, s, rm[tx + 64], rs[tx + 64]);
#pragma unroll
        for (int d = 1; d < 64; d <<= 1) {
          M = fmaxf(M, __shfl_xor(M, d));
          float m2 = __shfl_xor(m, d), s2 = __shfl_xor(s, d);
          lse_merge(m, s, m2, s2);
        }
        if (tx == 0) {
          sMax = M; scnt = 0;
          st_cf(wsf + OFF_LSEA + (t - 1) * B_ + b, m + logf(s));
        }
      }
      __syncthreads();
      if (cv >= sMax - DELTA && ci < V_) {
        int k = atomicAdd(&scnt, 1);
        if (k < 64) slist[k] = ci;
      }
      __syncthreads();
      const int nc = min(scnt, 64);
      float bV = -3.0e38f; int bI = 0x7fffffff;   // thread 0 carries
      for (int c = 0; c < nc; ++c) {
        const int idx = slist[c];
        rtmp[tx] = sh1a[tx] * p.Wo[(size_t)idx * H_ + tx];
        __syncthreads();
        if (tx < 256) rtmp[tx] += rtmp[tx + 256];
        __syncthreads();
        if (tx < 64) {
          float v = rtmp[tx] + rtmp[tx + 64] + rtmp[tx + 128] + rtmp[tx + 192];
#pragma unroll
          for (int d = 1; d < 64; d <<= 1) v += __shfl_xor(v, d);
          if (tx == 0) {
            float ex = v + p.bo[idx];
            if (ex > bV || (ex == bV && idx < bI)) { bV = ex; bI = idx; }
          }
        }
        __syncthreads();
      }
      if (tx == 0) st_ci(wsi + OFF_TOK + b, bI);
    }
    gbar(barp);
    // ================= Phase B: GRU layer 0 (all blocks) =================
    {
      float* sacts = (float*)SMEM;            // [4][768]
      float* sh0   = (float*)(SMEM + 12288);  // [4][512]
      {
        ull va[2], vh[2];
#pragma unroll
        for (int k = 0; k < 2; ++k) {
          const int iu = k * NTHR + tx;        // 0..1023
          const int bb = iu >> 8, cc = iu & 255;
          const ull* a1 = (const ull*)(wsf + OFF_INP) + (size_t)(b4 + bb) * 256 + cc;
          const ull* a2 = (const ull*)(wsf + OFF_H0 + par * BH) + (size_t)(b4 + bb) * 256 + cc;
          asm volatile("global_load_dwordx2 %0, %1, off sc0 sc1" : "=v"(va[k]) : "v"(a1));
          asm volatile("global_load_dwordx2 %0, %1, off sc0 sc1" : "=v"(vh[k]) : "v"(a2));
        }
        if (tx < 4) stok4[tx] = (t > 0) ? ld_ci(wsi + OFF_TOK + b4 + tx) : START_TOK;
        asm volatile("s_waitcnt vmcnt(0)" ::: "memory");
#pragma unroll
        for (int k = 0; k < 2; ++k) {
          const int iu = k * NTHR + tx;
          const int bb = iu >> 8, cc = iu & 255;
          *(ull*)&sacts[bb * 768 + 256 + cc * 2] = va[k];
          *(ull*)&sh0[bb * 512 + cc * 2] = vh[k];
        }
      }
      __syncthreads();
#pragma unroll
      for (int k = 0; k < 2; ++k) {
        const int idx = k * NTHR + tx;
        const int bb = idx >> 8, e = idx & 255;
        sacts[bb * 768 + e] = p.embed[(size_t)stok4[bb] * E_ + e];
      }
      __syncthreads();
      const int u = tx >> 5, l = tx & 31;
      const int j = ug * 16 + u;
      float red[16];
#pragma unroll
      for (int q = 0; q < 16; ++q) red[q] = 0.f;
#pragma unroll
      for (int g = 0; g < 3; ++g) {
        const float* wx = p.Wih0 + (size_t)(g * H_ + j) * 768 + l * 24;
        float* dx = (g < 2) ? &red[g * 4] : &red[8];
#pragma unroll
        for (int c = 0; c < 6; ++c) {
          const float4 w = *(const float4*)(wx + c * 4);
#pragma unroll
          for (int b2 = 0; b2 < 4; ++b2) {
            const float* a = &sacts[b2 * 768 + l * 24 + c * 4];
            dx[b2] = fmaf(w.x, a[0], dx[b2]); dx[b2] = fmaf(w.y, a[1], dx[b2]);
            dx[b2] = fmaf(w.z, a[2], dx[b2]); dx[b2] = fmaf(w.w, a[3], dx[b2]);
          }
        }
        const float* wh = p.Whh0 + (size_t)(g * H_ + j) * H_ + l * 16;
        float* dh = (g < 2) ? &red[g * 4] : &red[12];
#pragma unroll
        for (int c = 0; c < 4; ++c) {
          const float4 w = *(const float4*)(wh + c * 4);
#pragma unroll
          for (int b2 = 0; b2 < 4; ++b2) {
            const float* a = &sh0[b2 * 512 + l * 16 + c * 4];
            dh[b2] = fmaf(w.x, a[0], dh[b2]); dh[b2] = fmaf(w.y, a[1], dh[b2]);
            dh[b2] = fmaf(w.z, a[2], dh[b2]); dh[b2] = fmaf(w.w, a[3], dh[b2]);
          }
        }
      }
#pragma unroll
      for (int d = 1; d < 32; d <<= 1)
#pragma unroll
        for (int q = 0; q < 16; ++q) red[q] += __shfl_xor(red[q], d);
      if (l < 4) {
        const float rr = sigf(red[l] + p.bih0[j] + p.bhh0[j]);
        const float zz = sigf(red[4 + l] + p.bih0[H_ + j] + p.bhh0[H_ + j]);
        const float nn = tanhf(red[8 + l] + p.bih0[2 * H_ + j] +
                               rr * (red[12 + l] + p.bhh0[2 * H_ + j]));
        const float hp = sh0[l * 512 + j];
        st_cf(wsf + OFF_H0 + (1 - par) * BH + (size_t)(b4 + l) * H_ + j,
              (1.f - zz) * nn + zz * hp);
      }
    }
    gbar(barp);
    // ================= Phase C: GRU layer 1 + packs =================
    {
      float* sx = (float*)SMEM;                 // [4][512] h0_new
      float* sh = (float*)(SMEM + 8192);        // [4][512] h1_prev
      {
        ull vx[2], vh2[2];
#pragma unroll
        for (int k = 0; k < 2; ++k) {
          const int iu = k * NTHR + tx;
          const int bb = iu >> 8, cc = iu & 255;
          const ull* a1 = (const ull*)(wsf + OFF_H0 + (1 - par) * BH) + (size_t)(b4 + bb) * 256 + cc;
          const ull* a2 = (const ull*)(wsf + OFF_H1 + par * BH) + (size_t)(b4 + bb) * 256 + cc;
          asm volatile("global_load_dwordx2 %0, %1, off sc0 sc1" : "=v"(vx[k]) : "v"(a1));
          asm volatile("global_load_dwordx2 %0, %1, off sc0 sc1" : "=v"(vh2[k]) : "v"(a2));
        }
        asm volatile("s_waitcnt vmcnt(0)" ::: "memory");
#pragma unroll
        for (int k = 0; k < 2; ++k) {
          const int iu = k * NTHR + tx;
          const int bb = iu >> 8, cc = iu & 255;
          *(ull*)&sx[bb * 512 + cc * 2] = vx[k];
          *(ull*)&sh[bb * 512 + cc * 2] = vh2[k];
        }
      }
      __syncthreads();
      const int u = tx >> 5, l = tx & 31;
      const int j = ug * 16 + u;
      float red[16];
#pragma unroll
      for (int q = 0; q < 16; ++q) red[q] = 0.f;
#pragma unroll
      for (int g = 0; g < 3; ++g) {
        const float* wx = p.Wih1 + (size_t)(g * H_ + j) * H_ + l * 16;
        float* dx = (g < 2) ? &red[g * 4] : &red[8];
#pragma unroll
        for (int c = 0; c < 4; ++c) {
          const float4 w = *(const float4*)(wx + c * 4);
#pragma unroll
          for (int b2 = 0; b2 < 4; ++b2) {
            const float* a = &sx[b2 * 512 + l * 16 + c * 4];
            dx[b2] = fmaf(w.x, a[0], dx[b2]); dx[b2] = fmaf(w.y, a[1], dx[b2]);
            dx[b2] = fmaf(w.z, a[2], dx[b2]); dx[b2] = fmaf(w.w, a[3], dx[b2]);
          }
        }
        const float* wh = p.Whh1 + (size_t)(g * H_ + j) * H_ + l * 16;
        float* dh = (g < 2) ? &red[g * 4] : &red[12];
#pragma unroll
        for (int c = 0; c < 4; ++c) {
          const float4 w = *(const float4*)(wh + c * 4);
#pragma unroll
          for (int b2 = 0; b2 < 4; ++b2) {
            const float* a = &sh[b2 * 512 + l * 16 + c * 4];
            dh[b2] = fmaf(w.x, a[0], dh[b2]); dh[b2] = fmaf(w.y, a[1], dh[b2]);
            dh[b2] = fmaf(w.z, a[2], dh[b2]); dh[b2] = fmaf(w.w, a[3], dh[b2]);
          }
        }
      }
#pragma unroll
      for (int d = 1; d < 32; d <<= 1)
#pragma unroll
        for (int q = 0; q < 16; ++q) red[q] += __shfl_xor(red[q], d);
      if (l < 4) {
        const float rr = sigf(red[l] + p.bih1[j] + p.bhh1[j]);
        const float zz = sigf(red[4 + l] + p.bih1[H_ + j] + p.bhh1[H_ + j]);
        const float nn = tanhf(red[8 + l] + p.bih1[2 * H_ + j] +
                               rr * (red[12 + l] + p.bhh1[2 * H_ + j]));
        const float hp = sh[l * 512 + j];
        const float hnew = (1.f - zz) * nn + zz * hp;
        st_cf(wsf + OFF_H1 + (1 - par) * BH + (size_t)(b4 + l) * H_ + j, hnew);
        hout[u * 4 + l] = hnew;
      }
      __syncthreads();
      if (tx < 32) {   // bf16 pack (2 units / dword) -> h1bf[t]
        const int b2 = tx & 3, pp = tx >> 2;
        const float h0v = hout[(pp * 2) * 4 + b2];
        const float h1v = hout[(pp * 2 + 1) * 4 + b2];
        const unsigned pk = (unsigned)f2bf(h0v) | ((unsigned)f2bf(h1v) << 16);
        st_ci((int*)(h1bf + ((size_t)t * B_ + b4 + b2) * H_ + ug * 16 + pp * 2), (int)pk);
      }
    }
    gbar(barp);
    // ========== Phase D: LDS-resident bf16 MFMA vocab scan (250 blocks) ==========
    if (bk < ND) {
      const int v0 = bk * 128;
      char* stgB = SMEM;                               // [16][1024B] swizzled bf16 h1
      float (*scrF)[16][4] = (float(*)[16][4])(SMEM + 16384);
      int (*scrI2)[16][2] = (int(*)[16][2])(SMEM + 18432);
      const int w = tx >> 6, l = tx & 63, lr = l & 15, lq = l >> 4;
      for (int bt = 0; bt < 2; ++bt) {
        {  // stage h1bf btile (32 KB/step/block via sc0; swizzled LDS write)
          const ull* src = (const ull*)(h1bf + ((size_t)t * B_ + bt * 16) * H_);
          ull vv[4];
#pragma unroll
          for (int e = 0; e < 4; ++e) {
            const ull* ap = src + (size_t)tx * 4 + e;
            asm volatile("global_load_dwordx2 %0, %1, off sc0 sc1" : "=v"(vv[e]) : "v"(ap));
          }
          asm volatile("s_waitcnt vmcnt(0)" ::: "memory");
#pragma unroll
          for (int e = 0; e < 4; ++e) {
            const int uu = tx * 4 + e;                 // ull index 0..2047
            const int row = uu >> 7, wb = (uu & 127) * 8;
            const int base = wb & ~15, half = wb & 8;
            *(ull*)&stgB[row * 1024 + ((base ^ ((row & 7) << 4)) | half)] = vv[e];
          }
        }
        __syncthreads();
        f32x4 acc = {0.f, 0.f, 0.f, 0.f};
        const int vr = w * 16 + lr;
#pragma unroll
        for (int kc = 0; kc < 16; ++kc) {
          const int koff = kc * 64 + lq * 16;
          bf16x8 a = *(const bf16x8*)&stgB[lr * 1024 + (koff ^ ((lr & 7) << 4))];
          bf16x8 bf = *(const bf16x8*)&woL[vr * 1024 + (koff ^ ((lr & 7) << 4))];
          acc = __builtin_amdgcn_mfma_f32_16x16x32_bf16(a, bf, acc, 0, 0, 0);
        }
        const float bov = p.bo[v0 + vr];
        // per r (=batch lq*4+r): top2 + lse reduce over the 16 lr-lanes
#pragma unroll
        for (int r = 0; r < 4; ++r) {
          float v1 = acc[r] + bov, v2 = -3.0e38f;
          int i1 = v0 + vr, i2 = 0x7fffffff;
          float m = v1, s = 1.0f;
#pragma unroll
          for (int d = 1; d < 16; d <<= 1) {
            float w1 = __shfl_xor(v1, d); int j1 = __shfl_xor(i1, d);
            float w2 = __shfl_xor(v2, d); int j2 = __shfl_xor(i2, d);
            float m2 = __shfl_xor(m, d);  float s2 = __shfl_xor(s, d);
            if (w1 > v1 || (w1 == v1 && j1 < i1)) { v2 = v1; i2 = i1; v1 = w1; i1 = j1; }
            else if (w1 > v2 || (w1 == v2 && j1 < i2)) { v2 = w1; i2 = j1; }
            if (w2 > v2 || (w2 == v2 && j2 < i2)) {
              if (w2 > v1 || (w2 == v1 && j2 < i1)) { v2 = v1; i2 = i1; v1 = w2; i1 = j2; }
              else { v2 = w2; i2 = j2; }
            }
            lse_merge(m, s, m2, s2);
          }
          if (lr == 0) {
            const int bb = lq * 4 + r;
            scrF[w][bb][0] = v1; scrF[w][bb][1] = v2;
            scrF[w][bb][2] = m;  scrF[w][bb][3] = s;
            scrI2[w][bb][0] = i1; scrI2[w][bb][1] = i2;
          }
        }
        __syncthreads();
        if (tx < 16) {   // combine 8 waves, publish per-block partials
          float v1 = scrF[0][tx][0], v2 = scrF[0][tx][1];
          float m = scrF[0][tx][2], s = scrF[0][tx][3];
          int i1 = scrI2[0][tx][0], i2 = scrI2[0][tx][1];
#pragma unroll
          for (int ww = 1; ww < 8; ++ww) {
            float w1 = scrF[ww][tx][0]; int j1 = scrI2[ww][tx][0];
            float w2 = scrF[ww][tx][1]; int j2 = scrI2[ww][tx][1];
            if (w1 > v1 || (w1 == v1 && j1 < i1)) { v2 = v1; i2 = i1; v1 = w1; i1 = j1; }
            else if (w1 > v2 || (w1 == v2 && j1 < i2)) { v2 = w1; i2 = j1; }
            if (w2 > v2 || (w2 == v2 && j2 < i2)) {
              if (w2 > v1 || (w2 == v1 && j2 < i1)) { v2 = v1; i2 = i1; v1 = w2; i1 = j2; }
              else { v2 = w2; i2 = j2; }
            }
            lse_merge(m, s, scrF[ww][tx][2], scrF[ww][tx][3]);
          }
          const int b = bt * 16 + tx;
          st_cf(wsf + OFF_A2V + (size_t)b * 512 + bk * 2, v1);
          st_cf(wsf + OFF_A2V + (size_t)b * 512 + bk * 2 + 1, v2);
          st_ci(wsi + OFF_A2I + (size_t)b * 512 + bk * 2, i1);
          st_ci(wsi + OFF_A2I + (size_t)b * 512 + bk * 2 + 1, i2);
          st_cf(wsf + OFF_LSM + (size_t)b * 256 + bk, m);
          st_cf(wsf + OFF_LSS + (size_t)b * 256 + bk, s);
        }
        __syncthreads();
      }
    }
    if (t < T_ - 1) gbar(barp);
  }
}

// ---------------- epilogue: lse for last step ----------------
__global__ void __launch_bounds__(256) epi_lse(float* __restrict__ wsf) {
  const int b = blockIdx.x, tx = threadIdx.x;
  __shared__ float rm[256], rs[256];
  rm[tx] = (tx < ND) ? wsf[OFF_LSM + b * 256 + tx] : -3.0e38f;
  rs[tx] = (tx < ND) ? wsf[OFF_LSS + b * 256 + tx] : 0.f;
  __syncthreads();
  if (tx < 64) {
    float m = rm[tx], s = rs[tx];
#pragma unroll
    for (int o = 64; o < 256; o += 64) lse_merge(m, s, rm[tx + o], rs[tx + o]);
#pragma unroll
    for (int d = 1; d < 64; d <<= 1) {
      float m2 = __shfl_xor(m, d), s2 = __shfl_xor(s, d);
      lse_merge(m, s, m2, s2);
    }
    if (tx == 0) wsf[OFF_LSEA + 31 * B_ + b] = m + logf(s);
  }
}

// ---------------- final batched logp GEMM (bf16 MFMA) ----------------
__global__ void __launch_bounds__(256) gemm_logp(const unsigned short* __restrict__ h1bf,
                                                 const unsigned short* __restrict__ wobf,
                                                 const float* __restrict__ bo,
                                                 const float* __restrict__ lsea,
                                                 float* __restrict__ out) {
  __shared__ __align__(16) unsigned short As[2][128 * 40];  // rows padded to 80B
  __shared__ __align__(16) unsigned short Bs[2][128 * 40];
  const int tx = threadIdx.x;
  const int v0 = blockIdx.x * 128, m0 = blockIdx.y * 128;
  const int w = tx >> 6, l = tx & 63;
  const int wm = w >> 1, wn = w & 1;
  f32x4 acc[4][4];
#pragma unroll
  for (int i = 0; i < 4; ++i)
#pragma unroll
    for (int j = 0; j < 4; ++j) acc[i][j] = (f32x4){0.f, 0.f, 0.f, 0.f};

#define GSTAGE(ci, kc) {                                                        \
    _Pragma("unroll")                                                           \
    for (int e = 0; e < 2; ++e) {                                               \
      const int seg = tx * 2 + e, row = seg >> 2, s = seg & 3;                  \
      *(uint4*)&As[ci][row * 40 + s * 8] =                                      \
          *(const uint4*)(h1bf + (size_t)(m0 + row) * H_ + (kc) * 32 + s * 8);  \
      *(uint4*)&Bs[ci][row * 40 + s * 8] =                                      \
          *(const uint4*)(wobf + (size_t)(v0 + row) * H_ + (kc) * 32 + s * 8);  \
    } }

  GSTAGE(0, 0);
  __syncthreads();
  for (int kc = 0; kc < 16; ++kc) {
    const int cur = kc & 1;
    if (kc < 15) GSTAGE(cur ^ 1, kc + 1);
    const int lk = (l >> 4) * 8, lr = l & 15;
    bf16x8 af[4], bf[4];
#pragma unroll
    for (int f = 0; f < 4; ++f) {
      af[f] = *(const bf16x8*)&As[cur][(wm * 64 + f * 16 + lr) * 40 + lk];
      bf[f] = *(const bf16x8*)&Bs[cur][(wn * 64 + f * 16 + lr) * 40 + lk];
    }
#pragma unroll
    for (int fm = 0; fm < 4; ++fm)
#pragma unroll
      for (int fn = 0; fn < 4; ++fn)
        acc[fm][fn] = __builtin_amdgcn_mfma_f32_16x16x32_bf16(af[fm], bf[fn], acc[fm][fn], 0, 0, 0);
    __syncthreads();
  }
#undef GSTAGE
  const int lr = l & 15, lq = l >> 4;
#pragma unroll
  for (int fm = 0; fm < 4; ++fm) {
#pragma unroll
    for (int fn = 0; fn < 4; ++fn) {
      const int v = v0 + wn * 64 + fn * 16 + lr;
      const float bov = bo[v];
#pragma unroll
      for (int r = 0; r < 4; ++r) {
        const int M = m0 + wm * 64 + fm * 16 + lq * 4 + r;
        const int tt = M >> 5, b = M & 31;
        out[((size_t)b * T_ + tt) * (size_t)V_ + v] = acc[fm][fn][r] + bov - lsea[tt * B_ + b];
      }
    }
  }
}

// ---------------- host launch ----------------
extern "C" void kernel_launch(void* const* d_in, const int* in_sizes, int n_in,
                              void* d_out, int out_size, void* d_ws, size_t ws_size,
                              hipStream_t stream) {
  (void)in_sizes; (void)n_in; (void)out_size;
  if (ws_size < (size_t)WS_FLOATS * sizeof(float)) return;  // workspace too small

  const float* ctx   = (const float*)d_in[0];
  // d_in[1] = max_len (scalar, == 32, hardcoded)
  const float* embed = (const float*)d_in[2];
  const float* Wa    = (const float*)d_in[3];
  const float* ba    = (const float*)d_in[4];
  const float* Wih0  = (const float*)d_in[5];
  const float* Whh0  = (const float*)d_in[6];
  const float* bih0  = (const float*)d_in[7];
  const float* bhh0  = (const float*)d_in[8];
  const float* Wih1  = (const float*)d_in[9];
  const float* Whh1  = (const float*)d_in[10];
  const float* bih1  = (const float*)d_in[11];
  const float* bhh1  = (const float*)d_in[12];
  const float* Wo    = (const float*)d_in[13];
  const float* bo    = (const float*)d_in[14];
  float* ws  = (float*)d_ws;
  float* out = (float*)d_out;

  zero_k<<<dim3(256), dim3(256), 0, stream>>>(ws);
  cscore_k<<<dim3(32), dim3(256), 0, stream>>>(ctx, Wa, ba, ws);
  cvt_wobf<<<dim3(16000), dim3(256), 0, stream>>>(Wo, (unsigned short*)(ws + OFF_WOBF));

  Params p;
  p.ctx = ctx; p.embed = embed; p.Wa = Wa;
  p.Wih0 = Wih0; p.Whh0 = Whh0; p.bih0 = bih0; p.bhh0 = bhh0;
  p.Wih1 = Wih1; p.Whh1 = Whh1; p.bih1 = bih1; p.bhh1 = bhh1;
  p.Wo = Wo; p.bo = bo; p.ws = ws; p.out = out;
  mtad_main<<<dim3(NBLK), dim3(NTHR), 0, stream>>>(p);

  epi_lse<<<dim3(32), dim3(256), 0, stream>>>(ws);
  gemm_logp<<<dim3(250, 8), dim3(256), 0, stream>>>(
      (const unsigned short*)(ws + OFF_H1BF), (const unsigned short*)(ws + OFF_WOBF),
      bo, ws + OFF_LSEA, out);
}

// Round 6
// 3590.896 us; speedup vs baseline: 1.4789x; 1.0501x over previous
//
#include <hip/hip_runtime.h>

// ---------------- problem constants ----------------
#define B_ 32
#define S_ 64
#define C_ 512
#define E_ 256
#define H_ 512
#define V_ 32000
#define T_ 32
#define NBLK 256       // grid blocks (persistent kernel)
#define NTHR 512       // threads per block (8 waves)
#define ND 250         // scan blocks (250*128 = 32000)
#define START_TOK 1
#define DELTA 0.05f    // refine margin (bf16 logit err sigma ~6e-4)
#define BH (B_ * H_)

// ---------------- workspace layout (float offsets) ----------------
#define OFF_BAR  0          // barrier: 8 cnt @g*32, g8 @256, 8 gen lines @288+g*32
#define OFF_CS   512        // cscore[32][64]
#define OFF_LSEA 2560       // lse[32 t][32 b]
#define OFF_TOK  3584       // token[32] (int)
#define OFF_A2V  3648       // top2 cand value [32 b][512] (500 used)
#define OFF_A2I  20032      // top2 cand index [32 b][512] (int)
#define OFF_LSM  36416      // lse partial max [32][256] (250 used)
#define OFF_LSS  44608      // lse partial sum [32][256]
#define OFF_INP  52800      // attend [32 b][512]
#define OFF_H0   69184      // h0[2][32 b][512] ping-pong
#define OFF_H1   101952     // h1[2][32 b][512] ping-pong
#define OFF_H1BF 134720     // ushort[32 t * 32 b][512] bf16 h1 history
#define OFF_WOBF 396864     // ushort[32000][512] bf16 Wo
#define WS_FLOATS 8588864   // ~34.4 MB

typedef unsigned long long ull;
typedef __attribute__((ext_vector_type(8))) short bf16x8;
typedef __attribute__((ext_vector_type(4))) float f32x4;

struct Params {
  const float* ctx; const float* embed; const float* Wa;
  const float* Wih0; const float* Whh0; const float* bih0; const float* bhh0;
  const float* Wih1; const float* Whh1; const float* bih1; const float* bhh1;
  const float* Wo; const float* bo;
  float* ws; float* out;
};

__device__ __forceinline__ float sigf(float x) { return 1.0f / (1.0f + expf(-x)); }

__device__ __forceinline__ unsigned short f2bf(float f) {  // RNE f32->bf16
  unsigned u = __builtin_bit_cast(unsigned, f);
  unsigned r = (u + 0x7FFFu + ((u >> 16) & 1u)) >> 16;
  return (unsigned short)r;
}

__device__ __forceinline__ void lse_merge(float& m, float& s, float m2, float s2) {
  float M = fmaxf(m, m2);
  s = s * expf(m - M) + s2 * expf(m2 - M);
  m = M;
}

// ---- coherent (L2-bypass) access for mutable cross-block data ----
__device__ __forceinline__ float ld_cf(const float* p) {
  return __hip_atomic_load(p, __ATOMIC_RELAXED, __HIP_MEMORY_SCOPE_AGENT);
}
__device__ __forceinline__ void st_cf(float* p, float v) {
  __hip_atomic_store(p, v, __ATOMIC_RELAXED, __HIP_MEMORY_SCOPE_AGENT);
}
__device__ __forceinline__ int ld_ci(const int* p) {
  return __hip_atomic_load(p, __ATOMIC_RELAXED, __HIP_MEMORY_SCOPE_AGENT);
}
__device__ __forceinline__ void st_ci(int* p, int v) {
  __hip_atomic_store(p, v, __ATOMIC_RELAXED, __HIP_MEMORY_SCOPE_AGENT);
}

// -------- hierarchical grid barrier: per-group gen lines + poll backoff --------
// 8 group counters (32 blocks each) -> g8 -> releaser broadcasts gen+1 to 8
// per-group gen lines (128B apart). Each block polls ONLY its group's line with
// exponential backoff, so <=32 pollers per L3 line at a decaying rate.
__device__ __forceinline__ void gbar(unsigned* ws) {
  __syncthreads();
  if (threadIdx.x == 0) {
    const int gq = blockIdx.x & 7;
    unsigned* cnt = ws + (gq << 5);
    unsigned* g8  = ws + 256;
    unsigned* gen = ws + 288 + (gq << 5);
    asm volatile("s_waitcnt vmcnt(0) lgkmcnt(0)" ::: "memory");
    unsigned old = __hip_atomic_load(gen, __ATOMIC_RELAXED, __HIP_MEMORY_SCOPE_AGENT);
    asm volatile("s_waitcnt vmcnt(0)" ::: "memory");
    unsigned a = __hip_atomic_fetch_add(cnt, 1u, __ATOMIC_RELAXED, __HIP_MEMORY_SCOPE_AGENT);
    if (a == 31u) {
      __hip_atomic_store(cnt, 0u, __ATOMIC_RELAXED, __HIP_MEMORY_SCOPE_AGENT);
      asm volatile("s_waitcnt vmcnt(0)" ::: "memory");
      unsigned a2 = __hip_atomic_fetch_add(g8, 1u, __ATOMIC_RELAXED, __HIP_MEMORY_SCOPE_AGENT);
      if (a2 == 7u) {
        __hip_atomic_store(g8, 0u, __ATOMIC_RELAXED, __HIP_MEMORY_SCOPE_AGENT);
        asm volatile("s_waitcnt vmcnt(0)" ::: "memory");
#pragma unroll
        for (int gg = 0; gg < 8; ++gg)
          __hip_atomic_store(ws + 288 + (gg << 5), old + 1u,
                             __ATOMIC_RELAXED, __HIP_MEMORY_SCOPE_AGENT);
      }
    }
    int its = 0;
    while (__hip_atomic_load(gen, __ATOMIC_RELAXED, __HIP_MEMORY_SCOPE_AGENT) == old) {
      if (its < 6) __builtin_amdgcn_s_sleep(2);
      else if (its < 12) __builtin_amdgcn_s_sleep(8);
      else __builtin_amdgcn_s_sleep(32);
      ++its;
    }
    asm volatile("" ::: "memory");
  }
  __syncthreads();
}

// ---------------- prologue kernels ----------------
__global__ void __launch_bounds__(256) zero_k(float* wsf) {
  const unsigned i = blockIdx.x * 256u + threadIdx.x;
  if (i < 512u) ((unsigned*)wsf)[i] = 0u;
  if (i < 65536u) wsf[OFF_H0 + i] = 0.0f;   // h0[2] + h1[2] contiguous
}

__global__ void __launch_bounds__(256) cscore_k(const float* __restrict__ ctx,
                                                const float* __restrict__ Wa,
                                                const float* __restrict__ ba,
                                                float* __restrict__ wsf) {
  const int b = blockIdx.x;
  const int s = threadIdx.x >> 2, q = threadIdx.x & 3;
  const float* cp = ctx + ((size_t)b * S_ + s) * C_ + q * 128;
  const float* wp = Wa + H_ + q * 128;     // context half of Wa
  float acc = 0.f;
#pragma unroll 8
  for (int k = 0; k < 128; ++k) acc = fmaf(cp[k], wp[k], acc);
  acc += __shfl_xor(acc, 1);
  acc += __shfl_xor(acc, 2);
  if (q == 0) wsf[OFF_CS + b * S_ + s] = acc + ba[0];
}

__global__ void __launch_bounds__(256) cvt_wobf(const float* __restrict__ wo,
                                                unsigned short* __restrict__ dst) {
  const size_t i = ((size_t)blockIdx.x * 256u + threadIdx.x) * 4;
  float4 v = *(const float4*)(wo + i);
  ushort4 o;
  o.x = f2bf(v.x); o.y = f2bf(v.y); o.z = f2bf(v.z); o.w = f2bf(v.w);
  *(ushort4*)(dst + i) = o;
}

// ---------------- main persistent kernel ----------------
__global__ void __launch_bounds__(NTHR) mtad_main(Params p) {
  float* wsf = p.ws;
  int* wsi = (int*)p.ws;
  unsigned* barp = (unsigned*)p.ws;
  unsigned short* h1bf = (unsigned short*)(wsf + OFF_H1BF);
  const unsigned short* wobf = (const unsigned short*)(wsf + OFF_WOBF);
  const int bk = blockIdx.x, tx = threadIdx.x;
  const int ug = bk & 31, bg = bk >> 5, b4 = bg * 4;

  __shared__ __align__(16) unsigned char woL[131072];  // 128 KB: this block's 128 bf16 Wo rows
  __shared__ __align__(16) char SMEM[20480];           // phase-dependent blob
  __shared__ float wlds[64];
  __shared__ float hout[64];
  __shared__ int   stok4[4];
  __shared__ float shsS, sMax;
  __shared__ int   slist[64];
  __shared__ int   scnt;

  // ---------- prologue: fill woL (swizzled) from WOBF ----------
  if (bk < ND) {
    const unsigned short* src = wobf + (size_t)bk * 128 * H_;
    for (int c = tx; c < 8192; c += NTHR) {
      const int row = c >> 6, cc = c & 63;
      uint4 v = *(const uint4*)(src + (size_t)row * H_ + cc * 8);
      *(uint4*)&woL[row * 1024 + ((cc * 16) ^ ((row & 7) << 4))] = v;
    }
  }
  gbar(barp);

  for (int t = 0; t < T_; ++t) {
    const int par = t & 1;
    // ========== Phase A: attention (blocks 0..31) || resolve (32..63) ==========
    if (bk < B_) {
      const int b = bk;
      float* rv   = (float*)SMEM;            // [512]
      float* sh1a = (float*)(SMEM + 2048);   // [512]
      sh1a[tx] = ld_cf(wsf + OFF_H1 + par * BH + (size_t)b * H_ + tx);
      __syncthreads();
      rv[tx] = sh1a[tx] * p.Wa[tx];
      __syncthreads();
      if (tx < 64) {
        float v = 0.f;
#pragma unroll
        for (int o = 0; o < NTHR; o += 64) v += rv[tx + o];
#pragma unroll
        for (int d = 1; d < 64; d <<= 1) v += __shfl_xor(v, d);
        if (tx == 0) shsS = v;
      }
      __syncthreads();
      if (tx < S_) {
        float sc = tanhf(shsS + wsf[OFF_CS + b * S_ + tx]);
        float e = expf(sc); float sum = e;
#pragma unroll
        for (int d = 1; d < 64; d <<= 1) sum += __shfl_xor(sum, d);
        float w = e / sum; wlds[tx] = w;
        p.out[(size_t)B_ * T_ * V_ + ((size_t)b * T_ + t) * S_ + tx] = w;
      }
      __syncthreads();
      {
        float a0 = 0.f;
        const float* cb = p.ctx + (size_t)b * S_ * C_ + tx;
#pragma unroll 8
        for (int s2 = 0; s2 < S_; ++s2) a0 = fmaf(wlds[s2], cb[(size_t)s2 * C_], a0);
        st_cf(wsf + OFF_INP + (size_t)b * H_ + tx, a0);
      }
    } else if (bk < 2 * B_ && t > 0) {
      const int b = bk - B_;
      float* rm   = (float*)(SMEM + 4096);   // [256]
      float* rs   = (float*)(SMEM + 5120);   // [256]
      float* sh1a = (float*)(SMEM + 6144);   // [512]
      float* rtmp = (float*)(SMEM + 8192);   // [512]
      sh1a[tx] = ld_cf(wsf + OFF_H1 + par * BH + (size_t)b * H_ + tx);
      float cv = -3.0e38f; int ci = 0x7fffffff;
      if (tx < 2 * ND) {
        cv = ld_cf(wsf + OFF_A2V + (size_t)b * 512 + tx);
        ci = ld_ci(wsi + OFF_A2I + (size_t)b * 512 + tx);
      }
      if (tx < 256) {
        rm[tx] = (tx < ND) ? ld_cf(wsf + OFF_LSM + (size_t)b * 256 + tx) : -3.0e38f;
        rs[tx] = (tx < ND) ? ld_cf(wsf + OFF_LSS + (size_t)b * 256 + tx) : 0.f;
      }
      rtmp[tx] = cv;
      __syncthreads();
      if (tx < 256) rtmp[tx] = fmaxf(rtmp[tx], rtmp[tx + 256]);
      if (tx < 128) lse_merge(rm[tx], rs[tx], rm[tx + 128], rs[tx + 128]);
      __syncthreads();
      if (tx < 64) {
        float M = fmaxf(fmaxf(rtmp[tx], rtmp[tx + 64]),
                        fmaxf(rtmp[tx + 128], rtmp[tx + 192]));
        float m = rm[tx], s = rs[tx];
        lse_merge(m, s, rm[tx + 64], rs[tx + 64]);
#pragma unroll
        for (int d = 1; d < 64; d <<= 1) {
          M = fmaxf(M, __shfl_xor(M, d));
          float m2 = __shfl_xor(m, d), s2 = __shfl_xor(s, d);
          lse_merge(m, s, m2, s2);
        }
        if (tx == 0) {
          sMax = M; scnt = 0;
          st_cf(wsf + OFF_LSEA + (t - 1) * B_ + b, m + logf(s));
        }
      }
      __syncthreads();
      if (cv >= sMax - DELTA && ci < V_) {
        int k = atomicAdd(&scnt, 1);
        if (k < 64) slist[k] = ci;
      }
      __syncthreads();
      const int nc = min(scnt, 64);
      float bV = -3.0e38f; int bI = 0x7fffffff;   // thread 0 carries
      for (int c = 0; c < nc; ++c) {
        const int idx = slist[c];
        rtmp[tx] = sh1a[tx] * p.Wo[(size_t)idx * H_ + tx];
        __syncthreads();
        if (tx < 256) rtmp[tx] += rtmp[tx + 256];
        __syncthreads();
        if (tx < 64) {
          float v = rtmp[tx] + rtmp[tx + 64] + rtmp[tx + 128] + rtmp[tx + 192];
#pragma unroll
          for (int d = 1; d < 64; d <<= 1) v += __shfl_xor(v, d);
          if (tx == 0) {
            float ex = v + p.bo[idx];
            if (ex > bV || (ex == bV && idx < bI)) { bV = ex; bI = idx; }
          }
        }
        __syncthreads();
      }
      if (tx == 0) st_ci(wsi + OFF_TOK + b, bI);
    }
    gbar(barp);
    // ================= Phase B: GRU layer 0 (all blocks) =================
    {
      float* sacts = (float*)SMEM;            // [4][768]
      float* sh0   = (float*)(SMEM + 12288);  // [4][512]
      {
        ull va[2], vh[2];
#pragma unroll
        for (int k = 0; k < 2; ++k) {
          const int iu = k * NTHR + tx;        // 0..1023
          const int bb = iu >> 8, cc = iu & 255;
          const ull* a1 = (const ull*)(wsf + OFF_INP) + (size_t)(b4 + bb) * 256 + cc;
          const ull* a2 = (const ull*)(wsf + OFF_H0 + par * BH) + (size_t)(b4 + bb) * 256 + cc;
          asm volatile("global_load_dwordx2 %0, %1, off sc0 sc1" : "=v"(va[k]) : "v"(a1));
          asm volatile("global_load_dwordx2 %0, %1, off sc0 sc1" : "=v"(vh[k]) : "v"(a2));
        }
        if (tx < 4) stok4[tx] = (t > 0) ? ld_ci(wsi + OFF_TOK + b4 + tx) : START_TOK;
        asm volatile("s_waitcnt vmcnt(0)" ::: "memory");
#pragma unroll
        for (int k = 0; k < 2; ++k) {
          const int iu = k * NTHR + tx;
          const int bb = iu >> 8, cc = iu & 255;
          *(ull*)&sacts[bb * 768 + 256 + cc * 2] = va[k];
          *(ull*)&sh0[bb * 512 + cc * 2] = vh[k];
        }
      }
      __syncthreads();
#pragma unroll
      for (int k = 0; k < 2; ++k) {
        const int idx = k * NTHR + tx;
        const int bb = idx >> 8, e = idx & 255;
        sacts[bb * 768 + e] = p.embed[(size_t)stok4[bb] * E_ + e];
      }
      __syncthreads();
      // k-interleaved lanes: LDS reads lane-adjacent (conflict-free),
      // weight reads half-wave-contiguous (128B per 32 lanes)
      const int u = tx >> 5, l = tx & 31;
      const int j = ug * 16 + u;
      float red[16];
#pragma unroll
      for (int q = 0; q < 16; ++q) red[q] = 0.f;
#pragma unroll
      for (int g = 0; g < 3; ++g) {
        const float* wx = p.Wih0 + (size_t)(g * H_ + j) * 768 + l;
        float* dx = (g < 2) ? &red[g * 4] : &red[8];
#pragma unroll
        for (int c = 0; c < 24; ++c) {
          const float w = wx[32 * c];
          const int ai = l + 32 * c;
          dx[0] = fmaf(w, sacts[ai], dx[0]);
          dx[1] = fmaf(w, sacts[768 + ai], dx[1]);
          dx[2] = fmaf(w, sacts[1536 + ai], dx[2]);
          dx[3] = fmaf(w, sacts[2304 + ai], dx[3]);
        }
        const float* wh = p.Whh0 + (size_t)(g * H_ + j) * H_ + l;
        float* dh = (g < 2) ? &red[g * 4] : &red[12];
#pragma unroll
        for (int c = 0; c < 16; ++c) {
          const float w = wh[32 * c];
          const int ai = l + 32 * c;
          dh[0] = fmaf(w, sh0[ai], dh[0]);
          dh[1] = fmaf(w, sh0[512 + ai], dh[1]);
          dh[2] = fmaf(w, sh0[1024 + ai], dh[2]);
          dh[3] = fmaf(w, sh0[1536 + ai], dh[3]);
        }
      }
#pragma unroll
      for (int d = 1; d < 32; d <<= 1)
#pragma unroll
        for (int q = 0; q < 16; ++q) red[q] += __shfl_xor(red[q], d);
      if (l < 4) {
        const float rr = sigf(red[l] + p.bih0[j] + p.bhh0[j]);
        const float zz = sigf(red[4 + l] + p.bih0[H_ + j] + p.bhh0[H_ + j]);
        const float nn = tanhf(red[8 + l] + p.bih0[2 * H_ + j] +
                               rr * (red[12 + l] + p.bhh0[2 * H_ + j]));
        const float hp = sh0[l * 512 + j];
        st_cf(wsf + OFF_H0 + (1 - par) * BH + (size_t)(b4 + l) * H_ + j,
              (1.f - zz) * nn + zz * hp);
      }
    }
    gbar(barp);
    // ================= Phase C: GRU layer 1 + packs =================
    {
      float* sx = (float*)SMEM;                 // [4][512] h0_new
      float* sh = (float*)(SMEM + 8192);        // [4][512] h1_prev
      {
        ull vx[2], vh2[2];
#pragma unroll
        for (int k = 0; k < 2; ++k) {
          const int iu = k * NTHR + tx;
          const int bb = iu >> 8, cc = iu & 255;
          const ull* a1 = (const ull*)(wsf + OFF_H0 + (1 - par) * BH) + (size_t)(b4 + bb) * 256 + cc;
          const ull* a2 = (const ull*)(wsf + OFF_H1 + par * BH) + (size_t)(b4 + bb) * 256 + cc;
          asm volatile("global_load_dwordx2 %0, %1, off sc0 sc1" : "=v"(vx[k]) : "v"(a1));
          asm volatile("global_load_dwordx2 %0, %1, off sc0 sc1" : "=v"(vh2[k]) : "v"(a2));
        }
        asm volatile("s_waitcnt vmcnt(0)" ::: "memory");
#pragma unroll
        for (int k = 0; k < 2; ++k) {
          const int iu = k * NTHR + tx;
          const int bb = iu >> 8, cc = iu & 255;
          *(ull*)&sx[bb * 512 + cc * 2] = vx[k];
          *(ull*)&sh[bb * 512 + cc * 2] = vh2[k];
        }
      }
      __syncthreads();
      const int u = tx >> 5, l = tx & 31;
      const int j = ug * 16 + u;
      float red[16];
#pragma unroll
      for (int q = 0; q < 16; ++q) red[q] = 0.f;
#pragma unroll
      for (int g = 0; g < 3; ++g) {
        const float* wxp = p.Wih1 + (size_t)(g * H_ + j) * H_ + l;
        float* dx = (g < 2) ? &red[g * 4] : &red[8];
#pragma unroll
        for (int c = 0; c < 16; ++c) {
          const float w = wxp[32 * c];
          const int ai = l + 32 * c;
          dx[0] = fmaf(w, sx[ai], dx[0]);
          dx[1] = fmaf(w, sx[512 + ai], dx[1]);
          dx[2] = fmaf(w, sx[1024 + ai], dx[2]);
          dx[3] = fmaf(w, sx[1536 + ai], dx[3]);
        }
        const float* whp = p.Whh1 + (size_t)(g * H_ + j) * H_ + l;
        float* dh = (g < 2) ? &red[g * 4] : &red[12];
#pragma unroll
        for (int c = 0; c < 16; ++c) {
          const float w = whp[32 * c];
          const int ai = l + 32 * c;
          dh[0] = fmaf(w, sh[ai], dh[0]);
          dh[1] = fmaf(w, sh[512 + ai], dh[1]);
          dh[2] = fmaf(w, sh[1024 + ai], dh[2]);
          dh[3] = fmaf(w, sh[1536 + ai], dh[3]);
        }
      }
#pragma unroll
      for (int d = 1; d < 32; d <<= 1)
#pragma unroll
        for (int q = 0; q < 16; ++q) red[q] += __shfl_xor(red[q], d);
      if (l < 4) {
        const float rr = sigf(red[l] + p.bih1[j] + p.bhh1[j]);
        const float zz = sigf(red[4 + l] + p.bih1[H_ + j] + p.bhh1[H_ + j]);
        const float nn = tanhf(red[8 + l] + p.bih1[2 * H_ + j] +
                               rr * (red[12 + l] + p.bhh1[2 * H_ + j]));
        const float hp = sh[l * 512 + j];
        const float hnew = (1.f - zz) * nn + zz * hp;
        st_cf(wsf + OFF_H1 + (1 - par) * BH + (size_t)(b4 + l) * H_ + j, hnew);
        hout[u * 4 + l] = hnew;
      }
      __syncthreads();
      if (tx < 32) {   // bf16 pack (2 units / dword) -> h1bf[t]
        const int b2 = tx & 3, pp = tx >> 2;
        const float h0v = hout[(pp * 2) * 4 + b2];
        const float h1v = hout[(pp * 2 + 1) * 4 + b2];
        const unsigned pk = (unsigned)f2bf(h0v) | ((unsigned)f2bf(h1v) << 16);
        st_ci((int*)(h1bf + ((size_t)t * B_ + b4 + b2) * H_ + ug * 16 + pp * 2), (int)pk);
      }
    }
    gbar(barp);
    // ========== Phase D: LDS-resident bf16 MFMA vocab scan (250 blocks) ==========
    if (bk < ND) {
      const int v0 = bk * 128;
      char* stgB = SMEM;                               // [16][1024B] swizzled bf16 h1
      float (*scrF)[16][4] = (float(*)[16][4])(SMEM + 16384);
      int (*scrI2)[16][2] = (int(*)[16][2])(SMEM + 18432);
      const int w = tx >> 6, l = tx & 63, lr = l & 15, lq = l >> 4;
      for (int bt = 0; bt < 2; ++bt) {
        {  // stage h1bf btile (32 KB/step/block via sc0; swizzled LDS write)
          const ull* src = (const ull*)(h1bf + ((size_t)t * B_ + bt * 16) * H_);
          ull vv[4];
#pragma unroll
          for (int e = 0; e < 4; ++e) {
            const ull* ap = src + (size_t)tx * 4 + e;
            asm volatile("global_load_dwordx2 %0, %1, off sc0 sc1" : "=v"(vv[e]) : "v"(ap));
          }
          asm volatile("s_waitcnt vmcnt(0)" ::: "memory");
#pragma unroll
          for (int e = 0; e < 4; ++e) {
            const int uu = tx * 4 + e;                 // ull index 0..2047
            const int row = uu >> 7, wb = (uu & 127) * 8;
            const int base = wb & ~15, half = wb & 8;
            *(ull*)&stgB[row * 1024 + ((base ^ ((row & 7) << 4)) | half)] = vv[e];
          }
        }
        __syncthreads();
        f32x4 acc = {0.f, 0.f, 0.f, 0.f};
        const int vr = w * 16 + lr;
#pragma unroll
        for (int kc = 0; kc < 16; ++kc) {
          const int koff = kc * 64 + lq * 16;
          bf16x8 a = *(const bf16x8*)&stgB[lr * 1024 + (koff ^ ((lr & 7) << 4))];
          bf16x8 bf = *(const bf16x8*)&woL[vr * 1024 + (koff ^ ((lr & 7) << 4))];
          acc = __builtin_amdgcn_mfma_f32_16x16x32_bf16(a, bf, acc, 0, 0, 0);
        }
        const float bov = p.bo[v0 + vr];
        // per r (=batch lq*4+r): top2 + lse reduce over the 16 lr-lanes
#pragma unroll
        for (int r = 0; r < 4; ++r) {
          float v1 = acc[r] + bov, v2 = -3.0e38f;
          int i1 = v0 + vr, i2 = 0x7fffffff;
          float m = v1, s = 1.0f;
#pragma unroll
          for (int d = 1; d < 16; d <<= 1) {
            float w1 = __shfl_xor(v1, d); int j1 = __shfl_xor(i1, d);
            float w2 = __shfl_xor(v2, d); int j2 = __shfl_xor(i2, d);
            float m2 = __shfl_xor(m, d);  float s2 = __shfl_xor(s, d);
            if (w1 > v1 || (w1 == v1 && j1 < i1)) { v2 = v1; i2 = i1; v1 = w1; i1 = j1; }
            else if (w1 > v2 || (w1 == v2 && j1 < i2)) { v2 = w1; i2 = j1; }
            if (w2 > v2 || (w2 == v2 && j2 < i2)) {
              if (w2 > v1 || (w2 == v1 && j2 < i1)) { v2 = v1; i2 = i1; v1 = w2; i1 = j2; }
              else { v2 = w2; i2 = j2; }
            }
            lse_merge(m, s, m2, s2);
          }
          if (lr == 0) {
            const int bb = lq * 4 + r;
            scrF[w][bb][0] = v1; scrF[w][bb][1] = v2;
            scrF[w][bb][2] = m;  scrF[w][bb][3] = s;
            scrI2[w][bb][0] = i1; scrI2[w][bb][1] = i2;
          }
        }
        __syncthreads();
        if (tx < 16) {   // combine 8 waves, publish per-block partials
          float v1 = scrF[0][tx][0], v2 = scrF[0][tx][1];
          float m = scrF[0][tx][2], s = scrF[0][tx][3];
          int i1 = scrI2[0][tx][0], i2 = scrI2[0][tx][1];
#pragma unroll
          for (int ww = 1; ww < 8; ++ww) {
            float w1 = scrF[ww][tx][0]; int j1 = scrI2[ww][tx][0];
            float w2 = scrF[ww][tx][1]; int j2 = scrI2[ww][tx][1];
            if (w1 > v1 || (w1 == v1 && j1 < i1)) { v2 = v1; i2 = i1; v1 = w1; i1 = j1; }
            else if (w1 > v2 || (w1 == v2 && j1 < i2)) { v2 = w1; i2 = j1; }
            if (w2 > v2 || (w2 == v2 && j2 < i2)) {
              if (w2 > v1 || (w2 == v1 && j2 < i1)) { v2 = v1; i2 = i1; v1 = w2; i1 = j2; }
              else { v2 = w2; i2 = j2; }
            }
            lse_merge(m, s, scrF[ww][tx][2], scrF[ww][tx][3]);
          }
          const int b = bt * 16 + tx;
          st_cf(wsf + OFF_A2V + (size_t)b * 512 + bk * 2, v1);
          st_cf(wsf + OFF_A2V + (size_t)b * 512 + bk * 2 + 1, v2);
          st_ci(wsi + OFF_A2I + (size_t)b * 512 + bk * 2, i1);
          st_ci(wsi + OFF_A2I + (size_t)b * 512 + bk * 2 + 1, i2);
          st_cf(wsf + OFF_LSM + (size_t)b * 256 + bk, m);
          st_cf(wsf + OFF_LSS + (size_t)b * 256 + bk, s);
        }
        __syncthreads();
      }
    }
    if (t < T_ - 1) gbar(barp);
  }
}

// ---------------- epilogue: lse for last step ----------------
__global__ void __launch_bounds__(256) epi_lse(float* __restrict__ wsf) {
  const int b = blockIdx.x, tx = threadIdx.x;
  __shared__ float rm[256], rs[256];
  rm[tx] = (tx < ND) ? wsf[OFF_LSM + b * 256 + tx] : -3.0e38f;
  rs[tx] = (tx < ND) ? wsf[OFF_LSS + b * 256 + tx] : 0.f;
  __syncthreads();
  if (tx < 64) {
    float m = rm[tx], s = rs[tx];
#pragma unroll
    for (int o = 64; o < 256; o += 64) lse_merge(m, s, rm[tx + o], rs[tx + o]);
#pragma unroll
    for (int d = 1; d < 64; d <<= 1) {
      float m2 = __shfl_xor(m, d), s2 = __shfl_xor(s, d);
      lse_merge(m, s, m2, s2);
    }
    if (tx == 0) wsf[OFF_LSEA + 31 * B_ + b] = m + logf(s);
  }
}

// ---------------- final batched logp GEMM (bf16 MFMA) ----------------
__global__ void __launch_bounds__(256) gemm_logp(const unsigned short* __restrict__ h1bf,
                                                 const unsigned short* __restrict__ wobf,
                                                 const float* __restrict__ bo,
                                                 const float* __restrict__ lsea,
                                                 float* __restrict__ out) {
  __shared__ __align__(16) unsigned short As[2][128 * 40];  // rows padded to 80B
  __shared__ __align__(16) unsigned short Bs[2][128 * 40];
  const int tx = threadIdx.x;
  const int v0 = blockIdx.x * 128, m0 = blockIdx.y * 128;
  const int w = tx >> 6, l = tx & 63;
  const int wm = w >> 1, wn = w & 1;
  f32x4 acc[4][4];
#pragma unroll
  for (int i = 0; i < 4; ++i)
#pragma unroll
    for (int j = 0; j < 4; ++j) acc[i][j] = (f32x4){0.f, 0.f, 0.f, 0.f};

#define GSTAGE(ci, kc) {                                                        \
    _Pragma("unroll")                                                           \
    for (int e = 0; e < 2; ++e) {                                               \
      const int seg = tx * 2 + e, row = seg >> 2, s = seg & 3;                  \
      *(uint4*)&As[ci][row * 40 + s * 8] =                                      \
          *(const uint4*)(h1bf + (size_t)(m0 + row) * H_ + (kc) * 32 + s * 8);  \
      *(uint4*)&Bs[ci][row * 40 + s * 8] =                                      \
          *(const uint4*)(wobf + (size_t)(v0 + row) * H_ + (kc) * 32 + s * 8);  \
    } }

  GSTAGE(0, 0);
  __syncthreads();
  for (int kc = 0; kc < 16; ++kc) {
    const int cur = kc & 1;
    if (kc < 15) GSTAGE(cur ^ 1, kc + 1);
    const int lk = (l >> 4) * 8, lr = l & 15;
    bf16x8 af[4], bf[4];
#pragma unroll
    for (int f = 0; f < 4; ++f) {
      af[f] = *(const bf16x8*)&As[cur][(wm * 64 + f * 16 + lr) * 40 + lk];
      bf[f] = *(const bf16x8*)&Bs[cur][(wn * 64 + f * 16 + lr) * 40 + lk];
    }
#pragma unroll
    for (int fm = 0; fm < 4; ++fm)
#pragma unroll
      for (int fn = 0; fn < 4; ++fn)
        acc[fm][fn] = __builtin_amdgcn_mfma_f32_16x16x32_bf16(af[fm], bf[fn], acc[fm][fn], 0, 0, 0);
    __syncthreads();
  }
#undef GSTAGE
  const int lr = l & 15, lq = l >> 4;
#pragma unroll
  for (int fm = 0; fm < 4; ++fm) {
#pragma unroll
    for (int fn = 0; fn < 4; ++fn) {
      const int v = v0 + wn * 64 + fn * 16 + lr;
      const float bov = bo[v];
#pragma unroll
      for (int r = 0; r < 4; ++r) {
        const int M = m0 + wm * 64 + fm * 16 + lq * 4 + r;
        const int tt = M >> 5, b = M & 31;
        out[((size_t)b * T_ + tt) * (size_t)V_ + v] = acc[fm][fn][r] + bov - lsea[tt * B_ + b];
      }
    }
  }
}

// ---------------- host launch ----------------
extern "C" void kernel_launch(void* const* d_in, const int* in_sizes, int n_in,
                              void* d_out, int out_size, void* d_ws, size_t ws_size,
                              hipStream_t stream) {
  (void)in_sizes; (void)n_in; (void)out_size;
  if (ws_size < (size_t)WS_FLOATS * sizeof(float)) return;  // workspace too small

  const float* ctx   = (const float*)d_in[0];
  // d_in[1] = max_len (scalar, == 32, hardcoded)
  const float* embed = (const float*)d_in[2];
  const float* Wa    = (const float*)d_in[3];
  const float* ba    = (const float*)d_in[4];
  const float* Wih0  = (const float*)d_in[5];
  const float* Whh0  = (const float*)d_in[6];
  const float* bih0  = (const float*)d_in[7];
  const float* bhh0  = (const float*)d_in[8];
  const float* Wih1  = (const float*)d_in[9];
  const float* Whh1  = (const float*)d_in[10];
  const float* bih1  = (const float*)d_in[11];
  const float* bhh1  = (const float*)d_in[12];
  const float* Wo    = (const float*)d_in[13];
  const float* bo    = (const float*)d_in[14];
  float* ws  = (float*)d_ws;
  float* out = (float*)d_out;

  zero_k<<<dim3(256), dim3(256), 0, stream>>>(ws);
  cscore_k<<<dim3(32), dim3(256), 0, stream>>>(ctx, Wa, ba, ws);
  cvt_wobf<<<dim3(16000), dim3(256), 0, stream>>>(Wo, (unsigned short*)(ws + OFF_WOBF));

  Params p;
  p.ctx = ctx; p.embed = embed; p.Wa = Wa;
  p.Wih0 = Wih0; p.Whh0 = Whh0; p.bih0 = bih0; p.bhh0 = bhh0;
  p.Wih1 = Wih1; p.Whh1 = Whh1; p.bih1 = bih1; p.bhh1 = bhh1;
  p.Wo = Wo; p.bo = bo; p.ws = ws; p.out = out;
  mtad_main<<<dim3(NBLK), dim3(NTHR), 0, stream>>>(p);

  epi_lse<<<dim3(32), dim3(256), 0, stream>>>(ws);
  gemm_logp<<<dim3(250, 8), dim3(256), 0, stream>>>(
      (const unsigned short*)(ws + OFF_H1BF), (const unsigned short*)(ws + OFF_WOBF),
      bo, ws + OFF_LSEA, out);
}